// Round 12
// baseline (898.869 us; speedup 1.0000x reference)
//
#include <hip/hip_runtime.h>
#include <math.h>

// Problem constants (fixed by the reference)
#define B_SZ 2
#define L_SEQ 4096
#define D_MODEL 1024
#define D_INNER 2048
#define D_STATE 64
#define DT_RANK 128
#define BL (B_SZ * L_SEQ)          // 8192 tokens

#define AS1 __attribute__((address_space(1)))
#define AS3 __attribute__((address_space(3)))

typedef __attribute__((ext_vector_type(8))) short bf16x8_t;  // 8 bf16 = 4 VGPRs
typedef __attribute__((ext_vector_type(4))) float f32x4_t;
typedef __attribute__((ext_vector_type(2))) float f32x2_t;
typedef __attribute__((ext_vector_type(2))) unsigned int u32x2_t;

__device__ __forceinline__ unsigned short f2bf(float f) {
    unsigned int u = __float_as_uint(f);
    u = (u + 0x7FFFu + ((u >> 16) & 1u)) >> 16;   // RNE
    return (unsigned short)u;
}
__device__ __forceinline__ float bf2f(unsigned short h) {
    return __uint_as_float(((unsigned int)h) << 16);
}

// ---------------------------------------------------------------------------
// fp32 -> bf16 bulk convert (n4 = count of float4 groups)
// ---------------------------------------------------------------------------
__global__ __launch_bounds__(256) void cvt_f32_bf16(
    const float* __restrict__ in, unsigned short* __restrict__ out, int n4)
{
    int i = blockIdx.x * 256 + threadIdx.x;
    if (i >= n4) return;
    float4 v = ((const float4*)in)[i];
    ushort4 o;
    o.x = f2bf(v.x); o.y = f2bf(v.y); o.z = f2bf(v.z); o.w = f2bf(v.w);
    ((ushort4*)out)[i] = o;
}

// xdbl[:, :128] (fp32, row stride 256) -> packed bf16 [8192][128]
__global__ __launch_bounds__(256) void cvt_dtpart(
    const float* __restrict__ xdbl, unsigned short* __restrict__ out)
{
    int i = blockIdx.x * 256 + threadIdx.x;   // 0 .. 8192*32-1
    int m = i >> 5, c = i & 31;
    float4 v = *(const float4*)(xdbl + (size_t)m * 256 + c * 4);
    ushort4 o;
    o.x = f2bf(v.x); o.y = f2bf(v.y); o.z = f2bf(v.z); o.w = f2bf(v.w);
    ((ushort4*)(out))[(size_t)m * 32 + c] = o;
}

// B/C repack: bc2[t>>2][n][t&3] = xdbl[t][128+n]  (n=0..127; B at n<64, C at
// n>=64). Makes 4 consecutive steps' B (or C) for one lane a contiguous 16B
// quad -> scan reads b128 instead of 4x b32. 4MB r + 4MB w, ~4us.
__global__ __launch_bounds__(256) void repack_bc(
    const float* __restrict__ xdbl,   // [8192][256]
    float* __restrict__ bc2)          // [2048][128][4]
{
    int i = blockIdx.x * 256 + threadIdx.x;   // 0 .. 262143
    int t4 = i >> 7, n = i & 127;
    const float* s = xdbl + (size_t)(t4 * 4) * 256 + 128 + n;
    float4 o;
    o.x = s[0]; o.y = s[256]; o.z = s[512]; o.w = s[768];
    ((float4*)bc2)[i] = o;
}

// ---------------------------------------------------------------------------
// bf16 MFMA GEMM: C[m][n] = act( sum_k A[m][k]*B[n][k] [+ bias[m]] )
// ---------------------------------------------------------------------------
__global__ __launch_bounds__(256) void gemm_bf16(
    const unsigned short* __restrict__ A, int lda,
    const unsigned short* __restrict__ B, int ldb,
    float* __restrict__ C, int ldc, int K,
    const float* __restrict__ bias, int act)
{
    __shared__ unsigned short As[128 * 32];   // [row][k] linear, no pad
    __shared__ unsigned short Bs[128 * 32];

    const int tid = threadIdx.x;
    const int w = tid >> 6, lane = tid & 63;
    const int bm = blockIdx.y * 128, bn = blockIdx.x * 128;
    const int wm = (w & 1) * 64, wn = (w >> 1) * 64;

    f32x4_t acc[4][4];
#pragma unroll
    for (int i = 0; i < 4; ++i)
#pragma unroll
        for (int j = 0; j < 4; ++j) acc[i][j] = (f32x4_t){0.f, 0.f, 0.f, 0.f};

    const int srow = lane >> 2;
    const int scol = (lane & 3) * 8;
    const unsigned short* Ag0 = A + (size_t)(bm + w * 16 + srow) * lda + scol;
    const unsigned short* Ag1 = A + (size_t)(bm + 64 + w * 16 + srow) * lda + scol;
    const unsigned short* Bg0 = B + (size_t)(bn + w * 16 + srow) * ldb + scol;
    const unsigned short* Bg1 = B + (size_t)(bn + 64 + w * 16 + srow) * ldb + scol;
    unsigned short* la0 = &As[(w * 16) * 32];
    unsigned short* la1 = &As[(64 + w * 16) * 32];
    unsigned short* lb0 = &Bs[(w * 16) * 32];
    unsigned short* lb1 = &Bs[(64 + w * 16) * 32];

    const int fr = lane & 15;
    const int fk = (lane >> 4) * 8;

    for (int k0 = 0; k0 < K; k0 += 32) {
        __syncthreads();
        __builtin_amdgcn_global_load_lds((const AS1 void*)(Ag0 + k0), (AS3 void*)la0, 16, 0, 0);
        __builtin_amdgcn_global_load_lds((const AS1 void*)(Ag1 + k0), (AS3 void*)la1, 16, 0, 0);
        __builtin_amdgcn_global_load_lds((const AS1 void*)(Bg0 + k0), (AS3 void*)lb0, 16, 0, 0);
        __builtin_amdgcn_global_load_lds((const AS1 void*)(Bg1 + k0), (AS3 void*)lb1, 16, 0, 0);
        __syncthreads();

        bf16x8_t af[4], bfr[4];
#pragma unroll
        for (int i = 0; i < 4; ++i)
            af[i] = *(const bf16x8_t*)&As[(wm + i * 16 + fr) * 32 + fk];
#pragma unroll
        for (int j = 0; j < 4; ++j)
            bfr[j] = *(const bf16x8_t*)&Bs[(wn + j * 16 + fr) * 32 + fk];
#pragma unroll
        for (int i = 0; i < 4; ++i)
#pragma unroll
            for (int j = 0; j < 4; ++j)
                acc[i][j] = __builtin_amdgcn_mfma_f32_16x16x32_bf16(
                    af[i], bfr[j], acc[i][j], 0, 0, 0);
    }

    const int erow = (lane >> 4) * 4;
    const int ecol = lane & 15;
#pragma unroll
    for (int i = 0; i < 4; ++i) {
        int gr0 = bm + wm + i * 16 + erow;
#pragma unroll
        for (int j = 0; j < 4; ++j) {
            int gc = bn + wn + j * 16 + ecol;
#pragma unroll
            for (int r = 0; r < 4; ++r) {
                float v = acc[i][j][r];
                if (act == 1) {
                    float t = v + bias[gr0 + r];
                    v = (t > 20.f) ? t : log1pf(__expf(t));
                } else if (act == 2) {
                    v = v / (1.f + __expf(-v));
                }
                C[(size_t)(gr0 + r) * ldc + gc] = v;
            }
        }
    }
}

// ---------------------------------------------------------------------------
// causal depthwise conv (k=4) + bias + silu on [d][m] layout, bf16 output.
// ---------------------------------------------------------------------------
__global__ __launch_bounds__(256) void conv_silu_kernel(
    const float* __restrict__ xT,     // [2048][8192] fp32
    const float* __restrict__ w,      // [2048][4]
    const float* __restrict__ bias,   // [2048]
    unsigned short* __restrict__ xcT16) // [2048][8192] bf16
{
    int gid = blockIdx.x * blockDim.x + threadIdx.x;  // 0 .. 2048*2048-1
    int d = gid >> 11;
    int c4 = gid & 2047;
    int m0 = c4 * 4;
    int l0 = m0 & (L_SEQ - 1);

    const float* row = xT + (size_t)d * BL;
    float4 v = *(const float4*)(row + m0);
    float4 p;
    if (l0 == 0) { p.x = p.y = p.z = p.w = 0.f; }
    else         { p = *(const float4*)(row + m0 - 4); }

    float4 wv = ((const float4*)w)[d];
    float bb = bias[d];
    float e[4];
    e[0] = bb + wv.x * p.y + wv.y * p.z + wv.z * p.w + wv.w * v.x;
    e[1] = bb + wv.x * p.z + wv.y * p.w + wv.z * v.x + wv.w * v.y;
    e[2] = bb + wv.x * p.w + wv.y * v.x + wv.z * v.y + wv.w * v.z;
    e[3] = bb + wv.x * v.x + wv.y * v.y + wv.z * v.z + wv.w * v.w;
    ushort4 o;
    o.x = f2bf(e[0] / (1.f + __expf(-e[0])));
    o.y = f2bf(e[1] / (1.f + __expf(-e[1])));
    o.z = f2bf(e[2] / (1.f + __expf(-e[2])));
    o.w = f2bf(e[3] / (1.f + __expf(-e[3])));
    ((ushort4*)(xcT16 + (size_t)d * BL))[c4] = o;
}

// ---------------------------------------------------------------------------
// 32x32 tiled transposes (coalesced both sides)
// ---------------------------------------------------------------------------
__global__ __launch_bounds__(256) void transpose_f32_bf16(
    const float* __restrict__ in, int ldin,
    unsigned short* __restrict__ out, int ldout)
{
    __shared__ float tl[32][33];
    int r0 = blockIdx.y * 32, c0 = blockIdx.x * 32;
    int tx = threadIdx.x & 31, ty = threadIdx.x >> 5;
#pragma unroll
    for (int k = 0; k < 4; ++k)
        tl[ty + 8 * k][tx] = in[(size_t)(r0 + ty + 8 * k) * ldin + c0 + tx];
    __syncthreads();
#pragma unroll
    for (int k = 0; k < 4; ++k)
        out[(size_t)(c0 + ty + 8 * k) * ldout + r0 + tx] = f2bf(tl[tx][ty + 8 * k]);
}

__global__ __launch_bounds__(256) void transpose_bf16(
    const unsigned short* __restrict__ in, int ldin,
    unsigned short* __restrict__ out, int ldout)
{
    __shared__ unsigned short tl[32][33];
    int r0 = blockIdx.y * 32, c0 = blockIdx.x * 32;
    int tx = threadIdx.x & 31, ty = threadIdx.x >> 5;
#pragma unroll
    for (int k = 0; k < 4; ++k)
        tl[ty + 8 * k][tx] = in[(size_t)(r0 + ty + 8 * k) * ldin + c0 + tx];
    __syncthreads();
#pragma unroll
    for (int k = 0; k < 4; ++k)
        out[(size_t)(c0 + ty + 8 * k) * ldout + r0 + tx] = tl[tx][ty + 8 * k];
}

// ---------------------------------------------------------------------------
// Single-pass selective scan v8: ONE WAVE per (b,d); 4 waves/block sharing
// one batch's packed B/C via double-buffered 16-step LDS windows.
//   R10 post-mortem: v_pk packing worked (405->378, VALUBusy 81->74) but
//   OccupancyPercent=38% vs designed 50% (16 waves/CU): 512 blocks over
//   256 CUs with capacity EXACTLY 2 -> dispatch imbalance (a 3-block CU
//   forces a 1-block CU; critical path +50% on its share).
//   R11 change: 4-wave blocks (256 thr), SCHUNK=256, WSTEPS=16 ->
//   LDS 26KB -> capacity 6 blocks/CU for average load 4 (1024 blocks):
//   2 slots of slack absorb imbalance; 4-wave barriers are also cheaper.
//   GROUP16 math identical (one group per window).
// ---------------------------------------------------------------------------
#define SCHUNK 256
#define WSTEPS 16     // B/C window

#if __has_builtin(__builtin_amdgcn_permlane32_swap)
#define HAVE_PL32 1
#endif
#if __has_builtin(__builtin_amdgcn_permlane16_swap)
#define HAVE_PL16 1
#endif

// Packed fold stage 1 (xor32): pr2[i] (t=2i,2i+1) folded with pr2[i+4] (t+8).
// Per component: identical to R5-verified pl32_fold(x,y) = r.x + r.y.
#ifdef HAVE_PL32
#define FOLD_S1_PK                                                           \
    _Pragma("unroll")                                                        \
    for (int i = 0; i < 4; ++i) {                                            \
        f32x2_t xx = dir32 ? pr2[i + 4] : pr2[i];                            \
        f32x2_t yy = dir32 ? pr2[i] : pr2[i + 4];                            \
        u32x2_t ra = __builtin_amdgcn_permlane32_swap(                       \
            __float_as_uint(xx.x), __float_as_uint(yy.x), false, false);     \
        u32x2_t rb = __builtin_amdgcn_permlane32_swap(                       \
            __float_as_uint(xx.y), __float_as_uint(yy.y), false, false);     \
        f32x2_t va = {__uint_as_float(ra.x), __uint_as_float(rb.x)};         \
        f32x2_t vb = {__uint_as_float(ra.y), __uint_as_float(rb.y)};         \
        pr2[i] = va + vb;                                                    \
    }
#else
#define FOLD_S1_PK                                                           \
    _Pragma("unroll")                                                        \
    for (int i = 0; i < 4; ++i) {                                            \
        _Pragma("unroll")                                                    \
        for (int u = 0; u < 2; ++u) {                                        \
            float p0 = u ? pr2[i].y : pr2[i].x;                              \
            float p8 = u ? pr2[i + 4].y : pr2[i + 4].x;                      \
            float send = (lane & 32) ? p0 : p8;                              \
            float recv = __shfl_xor(send, 32);                               \
            float res = ((lane & 32) ? p8 : p0) + recv;                      \
            if (u) pr2[i].y = res; else pr2[i].x = res;                      \
        }                                                                    \
    }
#endif

// Packed fold stage 2 (xor16): pr2[i] folded with pr2[i+2], i<2.
#ifdef HAVE_PL16
#define FOLD_S2_PK                                                           \
    _Pragma("unroll")                                                        \
    for (int i = 0; i < 2; ++i) {                                            \
        f32x2_t xx = dir16 ? pr2[i + 2] : pr2[i];                            \
        f32x2_t yy = dir16 ? pr2[i] : pr2[i + 2];                            \
        u32x2_t ra = __builtin_amdgcn_permlane16_swap(                       \
            __float_as_uint(xx.x), __float_as_uint(yy.x), false, false);     \
        u32x2_t rb = __builtin_amdgcn_permlane16_swap(                       \
            __float_as_uint(xx.y), __float_as_uint(yy.y), false, false);     \
        f32x2_t va = {__uint_as_float(ra.x), __uint_as_float(rb.x)};         \
        f32x2_t vb = {__uint_as_float(ra.y), __uint_as_float(rb.y)};         \
        pr2[i] = va + vb;                                                    \
    }
#else
#define FOLD_S2_PK                                                           \
    _Pragma("unroll")                                                        \
    for (int i = 0; i < 2; ++i) {                                            \
        _Pragma("unroll")                                                    \
        for (int u = 0; u < 2; ++u) {                                        \
            float p0 = u ? pr2[i].y : pr2[i].x;                              \
            float p4 = u ? pr2[i + 2].y : pr2[i + 2].x;                      \
            float send = (lane & 16) ? p0 : p4;                              \
            float recv = __shfl_xor(send, 16);                               \
            float res = ((lane & 16) ? p4 : p0) + recv;                      \
            if (u) pr2[i].y = res; else pr2[i].x = res;                      \
        }                                                                    \
    }
#endif

// xor2 then xor1 butterfly on V: DPP quad_perm (stays within quads).
#if __has_builtin(__builtin_amdgcn_mov_dpp)
#define BFLY21(V)                                                            \
    V += __int_as_float(__builtin_amdgcn_mov_dpp(                            \
             __float_as_int(V), 0x4E, 0xF, 0xF, true));                      \
    V += __int_as_float(__builtin_amdgcn_mov_dpp(                            \
             __float_as_int(V), 0xB1, 0xF, 0xF, true));
#else
#define BFLY21(V)                                                            \
    V += __shfl_xor(V, 2);                                                   \
    V += __shfl_xor(V, 1);
#endif

// Cooperative async stage of window W's packed B/C (8KB linear = 8 units of
// 256 floats) into s_bc2[DB]. 4 waves x 2 issues; each global_load_lds
// covers one unit (64 lanes x 16B); unit = wid*2 + r_.
#define STAGE_BC(W, DB)                                                      \
{                                                                            \
    const float* wbase_ = bc2 + (size_t)(bQ + 4u * (unsigned)(W)) * 512;     \
    _Pragma("unroll")                                                        \
    for (int r_ = 0; r_ < 2; ++r_) {                                         \
        const float* src_ = wbase_ + (wid * 2 + r_) * 256 + lane * 4;        \
        __builtin_amdgcn_global_load_lds((const AS1 void*)src_,              \
            (AS3 void*)&s_bc2[DB][(wid * 2 + r_) * 256], 16, 0, 0);          \
    }                                                                        \
}

#define GROUP16(GG2, ZV)                                                     \
{                                                                            \
    const int gp = gpos + (GG2);        /* step base within chunk */         \
    const int t4b = (GG2) >> 2;                                              \
    f32x4_t bv4[4], cv4[4];                                                  \
    _Pragma("unroll")                                                        \
    for (int a = 0; a < 4; ++a) {       /* b128: 4 steps' B (or C) per read */\
        bv4[a] = *(const f32x4_t*)&sbcw[(t4b + a) * 512 + lane * 4];         \
        cv4[a] = *(const f32x4_t*)&sbcw[(t4b + a) * 512 + 256 + lane * 4];   \
    }                                                                        \
    f32x4_t d44[4], x44[4];                                                  \
    d44[0] = *(const f32x4_t*)&sdt[gp];                                      \
    d44[1] = *(const f32x4_t*)&sdt[gp + 4];                                  \
    d44[2] = *(const f32x4_t*)&sdt[gp + 8];                                  \
    d44[3] = *(const f32x4_t*)&sdt[gp + 12];                                 \
    x44[0] = *(const f32x4_t*)&sdtx[gp];                                     \
    x44[1] = *(const f32x4_t*)&sdtx[gp + 4];                                 \
    x44[2] = *(const f32x4_t*)&sdtx[gp + 8];                                 \
    x44[3] = *(const f32x4_t*)&sdtx[gp + 12];                                \
    f32x2_t e2[8], ib2[8], cvp[8];                                           \
    _Pragma("unroll")                                                        \
    for (int a = 0; a < 4; ++a) {       /* packed muls: v_pk_mul_f32 */      \
        e2[2*a]    = __builtin_shufflevector(d44[a], d44[a], 0, 1) * An2v;   \
        e2[2*a+1]  = __builtin_shufflevector(d44[a], d44[a], 2, 3) * An2v;   \
        ib2[2*a]   = __builtin_shufflevector(x44[a], x44[a], 0, 1)           \
                   * __builtin_shufflevector(bv4[a], bv4[a], 0, 1);          \
        ib2[2*a+1] = __builtin_shufflevector(x44[a], x44[a], 2, 3)           \
                   * __builtin_shufflevector(bv4[a], bv4[a], 2, 3);          \
        cvp[2*a]   = __builtin_shufflevector(cv4[a], cv4[a], 0, 1);          \
        cvp[2*a+1] = __builtin_shufflevector(cv4[a], cv4[a], 2, 3);          \
    }                                                                        \
    f32x2_t pr2[8];                                                          \
    _Pragma("unroll")                                                        \
    for (int i = 0; i < 8; ++i) {       /* serial h chain; packed h*C */     \
        float a0 = __builtin_amdgcn_exp2f(e2[i].x);                          \
        float a1 = __builtin_amdgcn_exp2f(e2[i].y);                          \
        f32x2_t hh;                                                          \
        h = fmaf(h, a0, ib2[i].x); hh.x = h;                                 \
        h = fmaf(h, a1, ib2[i].y); hh.y = h;                                 \
        pr2[i] = hh * cvp[i];                                                \
    }                                                                        \
    FOLD_S1_PK;                                                              \
    FOLD_S2_PK;                                                              \
    float prr[4] = {pr2[0].x, pr2[0].y, pr2[1].x, pr2[1].y};                 \
    _Pragma("unroll")                                                        \
    for (int t = 0; t < 2; ++t) {       /* fold xor8: 4 -> 2 */              \
        float send = (lane & 8) ? prr[t] : prr[t + 2];                       \
        float recv = __shfl_xor(send, 8);                                    \
        prr[t] = ((lane & 8) ? prr[t + 2] : prr[t]) + recv;                  \
    }                                                                        \
    {                                   /* fold xor4: 2 -> 1 */              \
        float send = (lane & 4) ? prr[0] : prr[1];                           \
        float recv = __shfl_xor(send, 4);                                    \
        prr[0] = ((lane & 4) ? prr[1] : prr[0]) + recv;                      \
    }                                                                        \
    BFLY21(prr[0]);                     /* butterfly over 4 n-residues */    \
    if ((lane & 3) == 0) {              /* 16 writer lanes, step (lane>>2)&15 */ \
        float xv = bf2f(sx[gp + myt16]);                                     \
        zrow[cbase + gp + myt16] = fmaf(Dd, xv, prr[0]) * (ZV);              \
    }                                                                        \
}

__global__ __launch_bounds__(256, 6) void scan_seq_kernel(
    const float* __restrict__ dtT,           // [2048][8192] fp32
    const unsigned short* __restrict__ xcT16,// [2048][8192] bf16
    const float* __restrict__ bc2,           // [2048][128][4] packed B/C
    float* __restrict__ zyT,                 // [2048][8192]: silu(z) in, y out
    const float* __restrict__ A_log,         // [2048][64]
    const float* __restrict__ Dp)            // [2048]
{
    __shared__ __align__(16) float s_dt[4][SCHUNK];           // 4 KB
    __shared__ __align__(16) float s_dtx[4][SCHUNK];          // 4 KB
    __shared__ __align__(16) unsigned short s_x[4][SCHUNK];   // 2 KB
    __shared__ __align__(16) float s_bc2[2][WSTEPS * 128];    // 16 KB (packed B/C)
    // 26 KB/block -> capacity 6 blocks/CU for avg load 4 (1024 blocks):
    // slack absorbs dispatch imbalance (R10's 38% occupancy).

    const int tid  = threadIdx.x;
    const int wid  = tid >> 6;              // 0..3
    const int lane = tid & 63;
    const int bi   = blockIdx.x;            // 0..1023; bi&1 constant per XCD
    const int b    = bi & 1;                // all 4 waves share b -> shared B/C
    const int d    = (bi >> 1) * 4 + wid;
    const unsigned bQ = (unsigned)b * (L_SEQ / 4);   // t4 offset of this batch

    const size_t rowbase = (size_t)d * BL + (size_t)(b * L_SEQ);
    const float An2 = -__expf(A_log[d * D_STATE + lane]) * 1.44269504f;
    const f32x2_t An2v = {An2, An2};
    const float Dd  = Dp[d];

    // permlane swap-direction probes (uniform, once; HW-verified in R5)
#ifdef HAVE_PL32
    bool dir32;
    {
        u32x2_t r = __builtin_amdgcn_permlane32_swap((unsigned)lane,
                        (unsigned)lane + 1000u, false, false);
        dir32 = (__builtin_amdgcn_readfirstlane(r.x) == 1032u);
    }
#endif
#ifdef HAVE_PL16
    bool dir16;
    {
        u32x2_t r = __builtin_amdgcn_permlane16_swap((unsigned)lane,
                        (unsigned)lane + 1000u, false, false);
        dir16 = (__builtin_amdgcn_readfirstlane(r.x) == 1016u);
    }
#endif

    float* sdt = s_dt[wid];
    float* sdtx = s_dtx[wid];
    unsigned short* sx = s_x[wid];
    const float* dtrow = dtT + rowbase;
    const unsigned short* xrow = xcT16 + rowbase;
    float* zrow = zyT + rowbase;
    const int myt16 = (lane >> 2) & 15;     // step index this lane ends up with

    // prefetch chunk 0: dt float4 (elems 4*lane..+3), x uint2 (same 4 elems)
    float4 pA = ((const float4*)dtrow)[lane];
    uint2  pX = ((const uint2*)xrow)[lane];

    float h = 0.f;
    int buf = 0;

    STAGE_BC(0, 0);                          // prologue: window 0 -> buf 0
    __syncthreads();

    for (int c = 0; c < L_SEQ / SCHUNK; ++c) {
        // stage current chunk's dt/x/dtx to this wave's private LDS slice.
        // dtx = dt*x computed ONCE here (amortized over 16 groups).
        ((float4*)sdt)[lane] = pA;
        ((uint2*)sx)[lane]   = pX;
        float4 dxA;
        dxA.x = pA.x * __uint_as_float(pX.x << 16);
        dxA.y = pA.y * __uint_as_float(pX.x & 0xffff0000u);
        dxA.z = pA.z * __uint_as_float(pX.y << 16);
        dxA.w = pA.w * __uint_as_float(pX.y & 0xffff0000u);
        ((float4*)sdtx)[lane] = dxA;

        if (c < L_SEQ / SCHUNK - 1) {       // register-prefetch next chunk
            pA = ((const float4*)(dtrow + (c + 1) * SCHUNK))[lane];
            pX = ((const uint2*)(xrow + (c + 1) * SCHUNK))[lane];
        }
        const int cbase = c * SCHUNK;

        for (int wd = 0; wd < SCHUNK / WSTEPS; ++wd) {
            const int wglob = c * (SCHUNK / WSTEPS) + wd;
            if (wglob + 1 < L_SEQ / WSTEPS)  // issue next window's staging EARLY
                STAGE_BC(wglob + 1, buf ^ 1);
            const int gpos = wd * WSTEPS;
            // hoist z: full-group latency cover
            float zv0 = 0.f;
            if ((lane & 3) == 0) zv0 = zrow[cbase + gpos + myt16];
            const float* sbcw = s_bc2[buf];
            GROUP16(0, zv0);
            __syncthreads();                 // staging had a full window to land
            buf ^= 1;
        }
    }
}

// ---------------------------------------------------------------------------
extern "C" void kernel_launch(void* const* d_in, const int* in_sizes, int n_in,
                              void* d_out, int out_size, void* d_ws, size_t ws_size,
                              hipStream_t stream)
{
    const float* hs        = (const float*)d_in[0];  // [8192][1024]
    const float* in_proj_w = (const float*)d_in[1];  // [4096][1024]
    const float* conv_w    = (const float*)d_in[2];  // [2048][4]
    const float* conv_b    = (const float*)d_in[3];  // [2048]
    const float* x_proj_w  = (const float*)d_in[4];  // [256][2048]
    const float* dt_proj_w = (const float*)d_in[5];  // [2048][128]
    const float* dt_proj_b = (const float*)d_in[6];  // [2048]
    const float* A_log     = (const float*)d_in[7];  // [2048][64]
    const float* Dp        = (const float*)d_in[8];  // [2048]
    const float* out_proj_w= (const float*)d_in[9];  // [1024][2048]
    float* out = (float*)d_out;                      // [8192][1024]

    // workspace map (MiB offsets; peak ~177.5 MiB):
    //  S0 @0   : xT fp32 (64) -> xc16 bf16 (32) @0 -> dtT fp32 (64) @0
    //  S1 @64  : zT fp32 (64)  (scan writes y in place)
    //  S2 @128 : W1_16 (8)@128 + hs16 (16)@136 -> xcT16 bf16 (32)@128 -> y16 (32)@128
    //  tail    : xdbl fp32 (8)@160, xdbl16 (2)@169 -> bc2 (4)@169 (xdbl16,
    //            Wx16, Wdt16 all dead by repack time), Wx16 (1)@171,
    //            Wdt16 (.5)@172, Wo16 (4)@173  (end 177)
    char* ws = (char*)d_ws;
    const size_t MiB = 1024 * 1024;
    float*          xT    = (float*)(ws);
    unsigned short* xc16  = (unsigned short*)(ws);
    float*          dtT   = (float*)(ws);
    float*          zT    = (float*)(ws + 64 * MiB);
    unsigned short* W1_16 = (unsigned short*)(ws + 128 * MiB);
    unsigned short* hs16  = (unsigned short*)(ws + 136 * MiB);
    unsigned short* xcT16 = (unsigned short*)(ws + 128 * MiB);
    unsigned short* y16   = (unsigned short*)(ws + 128 * MiB);
    float*          xdbl  = (float*)(ws + 160 * MiB);
    unsigned short* xdbl16= (unsigned short*)(ws + 169 * MiB);
    float*          bc2   = (float*)(ws + 169 * MiB);   // reuses dead region
    unsigned short* Wx16  = (unsigned short*)(ws + 171 * MiB);
    unsigned short* Wdt16 = (unsigned short*)(ws + 172 * MiB);
    unsigned short* Wo16  = (unsigned short*)(ws + 173 * MiB);

    dim3 blk(256);

    // bf16 conversions
    cvt_f32_bf16<<<8192, blk, 0, stream>>>(hs, hs16, 2097152);
    cvt_f32_bf16<<<4096, blk, 0, stream>>>(in_proj_w, W1_16, 1048576);
    cvt_f32_bf16<<<512, blk, 0, stream>>>(x_proj_w, Wx16, 131072);
    cvt_f32_bf16<<<256, blk, 0, stream>>>(dt_proj_w, Wdt16, 65536);
    cvt_f32_bf16<<<2048, blk, 0, stream>>>(out_proj_w, Wo16, 524288);

    // 1) xT[d][m] = W1x . hs^T   (M=2048, N=8192, K=1024)
    gemm_bf16<<<dim3(64, 16), blk, 0, stream>>>(
        W1_16, D_MODEL, hs16, D_MODEL, xT, BL, D_MODEL, nullptr, 0);

    // 2) zT[d][m] = silu(W1z . hs^T)
    gemm_bf16<<<dim3(64, 16), blk, 0, stream>>>(
        W1_16 + (size_t)D_INNER * D_MODEL, D_MODEL, hs16, D_MODEL,
        zT, BL, D_MODEL, nullptr, 2);

    // 3) xcT16 = bf16(silu(conv(xT) + b))
    conv_silu_kernel<<<(D_INNER * (BL / 4)) / 256, blk, 0, stream>>>(
        xT, conv_w, conv_b, xcT16);

    // 4) xc16[m][d] = transpose(xcT16)
    transpose_bf16<<<dim3(BL / 32, D_INNER / 32), blk, 0, stream>>>(
        xcT16, BL, xc16, D_INNER);

    // 5) xdbl[m][256] = xc . x_proj^T   (M=8192, N=256, K=2048)
    gemm_bf16<<<dim3(2, 64), blk, 0, stream>>>(
        xc16, D_INNER, Wx16, D_INNER, xdbl, 256, D_INNER, nullptr, 0);

    // 6) xdbl16 = bf16(xdbl[:, :128])
    cvt_dtpart<<<1024, blk, 0, stream>>>(xdbl, xdbl16);

    // 7) dtT[d][m] = softplus(Wdt . xdbl_dt^T + b[d])  (M=2048, N=8192, K=128)
    gemm_bf16<<<dim3(64, 16), blk, 0, stream>>>(
        Wdt16, DT_RANK, xdbl16, DT_RANK, dtT, BL, DT_RANK, dt_proj_b, 1);

    // 7b) pack B/C for b128 LDS reads in the scan
    repack_bc<<<1024, blk, 0, stream>>>(xdbl, bc2);

    // 8) single-pass scan: 1 wave per (b,d), 4 waves/block, packed B/C LDS
    scan_seq_kernel<<<1024, dim3(256), 0, stream>>>(
        dtT, xcT16, bc2, zT, A_log, Dp);

    // 9) y16[m][d] = bf16(transpose(zT))
    transpose_f32_bf16<<<dim3(BL / 32, D_INNER / 32), blk, 0, stream>>>(
        zT, BL, y16, D_INNER);

    // 10) out = y . out_proj^T   (M=8192, N=1024, K=2048)
    gemm_bf16<<<dim3(8, 64), blk, 0, stream>>>(
        y16, D_INNER, Wo16, D_INNER, out, D_MODEL, D_INNER, nullptr, 0);
}

// Round 13
// 838.698 us; speedup vs baseline: 1.0717x; 1.0717x over previous
//
#include <hip/hip_runtime.h>
#include <math.h>

// Problem constants (fixed by the reference)
#define B_SZ 2
#define L_SEQ 4096
#define D_MODEL 1024
#define D_INNER 2048
#define D_STATE 64
#define DT_RANK 128
#define BL (B_SZ * L_SEQ)          // 8192 tokens

#define AS1 __attribute__((address_space(1)))
#define AS3 __attribute__((address_space(3)))

typedef __attribute__((ext_vector_type(8))) short bf16x8_t;  // 8 bf16 = 4 VGPRs
typedef __attribute__((ext_vector_type(4))) float f32x4_t;
typedef __attribute__((ext_vector_type(2))) float f32x2_t;
typedef __attribute__((ext_vector_type(2))) unsigned int u32x2_t;

__device__ __forceinline__ unsigned short f2bf(float f) {
    unsigned int u = __float_as_uint(f);
    u = (u + 0x7FFFu + ((u >> 16) & 1u)) >> 16;   // RNE
    return (unsigned short)u;
}
__device__ __forceinline__ float bf2f(unsigned short h) {
    return __uint_as_float(((unsigned int)h) << 16);
}

// ---------------------------------------------------------------------------
// fp32 -> bf16 bulk convert (n4 = count of float4 groups)
// ---------------------------------------------------------------------------
__global__ __launch_bounds__(256) void cvt_f32_bf16(
    const float* __restrict__ in, unsigned short* __restrict__ out, int n4)
{
    int i = blockIdx.x * 256 + threadIdx.x;
    if (i >= n4) return;
    float4 v = ((const float4*)in)[i];
    ushort4 o;
    o.x = f2bf(v.x); o.y = f2bf(v.y); o.z = f2bf(v.z); o.w = f2bf(v.w);
    ((ushort4*)out)[i] = o;
}

// Merged: xdbl[:, :128] -> bf16 [8192][128]  (blocks 0..1023)
//         xdbl[:, 128:256] -> bc2[t>>2][n][t&3] packed B/C (blocks 1024..2047)
// bc2 layout makes 4 consecutive steps' B (or C) for one lane a contiguous
// 16B quad -> scan reads b128 instead of 4x b32.
__global__ __launch_bounds__(256) void cvt_dt_repack(
    const float* __restrict__ xdbl,   // [8192][256]
    unsigned short* __restrict__ out16, // [8192][128] bf16
    float* __restrict__ bc2)          // [2048][128][4]
{
    int bid = blockIdx.x;
    if (bid < 1024) {
        int i = bid * 256 + threadIdx.x;   // 0 .. 262143
        int m = i >> 5, c = i & 31;
        float4 v = *(const float4*)(xdbl + (size_t)m * 256 + c * 4);
        ushort4 o;
        o.x = f2bf(v.x); o.y = f2bf(v.y); o.z = f2bf(v.z); o.w = f2bf(v.w);
        ((ushort4*)(out16))[(size_t)m * 32 + c] = o;
    } else {
        int i = (bid - 1024) * 256 + threadIdx.x;  // 0 .. 262143
        int t4 = i >> 7, n = i & 127;
        const float* s = xdbl + (size_t)(t4 * 4) * 256 + 128 + n;
        float4 o;
        o.x = s[0]; o.y = s[256]; o.z = s[512]; o.w = s[768];
        ((float4*)bc2)[i] = o;
    }
}

// ---------------------------------------------------------------------------
// bf16 MFMA GEMM: C[m][n] = act( sum_k A[m][k]*B[n][k] [+ bias[m]] )
// act: 0 none, 1 softplus (bias by row), 2 silu, 3 row-split (rows >= 2048
// get silu, below none -- used by the merged x/z in-projection).
// ---------------------------------------------------------------------------
__global__ __launch_bounds__(256) void gemm_bf16(
    const unsigned short* __restrict__ A, int lda,
    const unsigned short* __restrict__ B, int ldb,
    float* __restrict__ C, int ldc, int K,
    const float* __restrict__ bias, int act)
{
    __shared__ unsigned short As[128 * 32];   // [row][k] linear, no pad
    __shared__ unsigned short Bs[128 * 32];

    const int tid = threadIdx.x;
    const int w = tid >> 6, lane = tid & 63;
    const int bm = blockIdx.y * 128, bn = blockIdx.x * 128;
    const int wm = (w & 1) * 64, wn = (w >> 1) * 64;

    f32x4_t acc[4][4];
#pragma unroll
    for (int i = 0; i < 4; ++i)
#pragma unroll
        for (int j = 0; j < 4; ++j) acc[i][j] = (f32x4_t){0.f, 0.f, 0.f, 0.f};

    const int srow = lane >> 2;
    const int scol = (lane & 3) * 8;
    const unsigned short* Ag0 = A + (size_t)(bm + w * 16 + srow) * lda + scol;
    const unsigned short* Ag1 = A + (size_t)(bm + 64 + w * 16 + srow) * lda + scol;
    const unsigned short* Bg0 = B + (size_t)(bn + w * 16 + srow) * ldb + scol;
    const unsigned short* Bg1 = B + (size_t)(bn + 64 + w * 16 + srow) * ldb + scol;
    unsigned short* la0 = &As[(w * 16) * 32];
    unsigned short* la1 = &As[(64 + w * 16) * 32];
    unsigned short* lb0 = &Bs[(w * 16) * 32];
    unsigned short* lb1 = &Bs[(64 + w * 16) * 32];

    const int fr = lane & 15;
    const int fk = (lane >> 4) * 8;

    for (int k0 = 0; k0 < K; k0 += 32) {
        __syncthreads();
        __builtin_amdgcn_global_load_lds((const AS1 void*)(Ag0 + k0), (AS3 void*)la0, 16, 0, 0);
        __builtin_amdgcn_global_load_lds((const AS1 void*)(Ag1 + k0), (AS3 void*)la1, 16, 0, 0);
        __builtin_amdgcn_global_load_lds((const AS1 void*)(Bg0 + k0), (AS3 void*)lb0, 16, 0, 0);
        __builtin_amdgcn_global_load_lds((const AS1 void*)(Bg1 + k0), (AS3 void*)lb1, 16, 0, 0);
        __syncthreads();

        bf16x8_t af[4], bfr[4];
#pragma unroll
        for (int i = 0; i < 4; ++i)
            af[i] = *(const bf16x8_t*)&As[(wm + i * 16 + fr) * 32 + fk];
#pragma unroll
        for (int j = 0; j < 4; ++j)
            bfr[j] = *(const bf16x8_t*)&Bs[(wn + j * 16 + fr) * 32 + fk];
#pragma unroll
        for (int i = 0; i < 4; ++i)
#pragma unroll
            for (int j = 0; j < 4; ++j)
                acc[i][j] = __builtin_amdgcn_mfma_f32_16x16x32_bf16(
                    af[i], bfr[j], acc[i][j], 0, 0, 0);
    }

    const int erow = (lane >> 4) * 4;
    const int ecol = lane & 15;
#pragma unroll
    for (int i = 0; i < 4; ++i) {
        int gr0 = bm + wm + i * 16 + erow;
#pragma unroll
        for (int j = 0; j < 4; ++j) {
            int gc = bn + wn + j * 16 + ecol;
#pragma unroll
            for (int r = 0; r < 4; ++r) {
                float v = acc[i][j][r];
                if (act == 1) {
                    float t = v + bias[gr0 + r];
                    v = (t > 20.f) ? t : log1pf(__expf(t));
                } else if (act == 2) {
                    v = v / (1.f + __expf(-v));
                } else if (act == 3 && gr0 >= 2048) {
                    v = v / (1.f + __expf(-v));
                }
                C[(size_t)(gr0 + r) * ldc + gc] = v;
            }
        }
    }
}

// ---------------------------------------------------------------------------
// causal depthwise conv (k=4) + bias + silu on [d][m] layout, bf16 output.
// ---------------------------------------------------------------------------
__global__ __launch_bounds__(256) void conv_silu_kernel(
    const float* __restrict__ xT,     // [2048][8192] fp32
    const float* __restrict__ w,      // [2048][4]
    const float* __restrict__ bias,   // [2048]
    unsigned short* __restrict__ xcT16) // [2048][8192] bf16
{
    int gid = blockIdx.x * blockDim.x + threadIdx.x;  // 0 .. 2048*2048-1
    int d = gid >> 11;
    int c4 = gid & 2047;
    int m0 = c4 * 4;
    int l0 = m0 & (L_SEQ - 1);

    const float* row = xT + (size_t)d * BL;
    float4 v = *(const float4*)(row + m0);
    float4 p;
    if (l0 == 0) { p.x = p.y = p.z = p.w = 0.f; }
    else         { p = *(const float4*)(row + m0 - 4); }

    float4 wv = ((const float4*)w)[d];
    float bb = bias[d];
    float e[4];
    e[0] = bb + wv.x * p.y + wv.y * p.z + wv.z * p.w + wv.w * v.x;
    e[1] = bb + wv.x * p.z + wv.y * p.w + wv.z * v.x + wv.w * v.y;
    e[2] = bb + wv.x * p.w + wv.y * v.x + wv.z * v.y + wv.w * v.z;
    e[3] = bb + wv.x * v.x + wv.y * v.y + wv.z * v.z + wv.w * v.w;
    ushort4 o;
    o.x = f2bf(e[0] / (1.f + __expf(-e[0])));
    o.y = f2bf(e[1] / (1.f + __expf(-e[1])));
    o.z = f2bf(e[2] / (1.f + __expf(-e[2])));
    o.w = f2bf(e[3] / (1.f + __expf(-e[3])));
    ((ushort4*)(xcT16 + (size_t)d * BL))[c4] = o;
}

// ---------------------------------------------------------------------------
// 32x32 tiled transposes (coalesced both sides)
// ---------------------------------------------------------------------------
__global__ __launch_bounds__(256) void transpose_f32_bf16(
    const float* __restrict__ in, int ldin,
    unsigned short* __restrict__ out, int ldout)
{
    __shared__ float tl[32][33];
    int r0 = blockIdx.y * 32, c0 = blockIdx.x * 32;
    int tx = threadIdx.x & 31, ty = threadIdx.x >> 5;
#pragma unroll
    for (int k = 0; k < 4; ++k)
        tl[ty + 8 * k][tx] = in[(size_t)(r0 + ty + 8 * k) * ldin + c0 + tx];
    __syncthreads();
#pragma unroll
    for (int k = 0; k < 4; ++k)
        out[(size_t)(c0 + ty + 8 * k) * ldout + r0 + tx] = f2bf(tl[tx][ty + 8 * k]);
}

__global__ __launch_bounds__(256) void transpose_bf16(
    const unsigned short* __restrict__ in, int ldin,
    unsigned short* __restrict__ out, int ldout)
{
    __shared__ unsigned short tl[32][33];
    int r0 = blockIdx.y * 32, c0 = blockIdx.x * 32;
    int tx = threadIdx.x & 31, ty = threadIdx.x >> 5;
#pragma unroll
    for (int k = 0; k < 4; ++k)
        tl[ty + 8 * k][tx] = in[(size_t)(r0 + ty + 8 * k) * ldin + c0 + tx];
    __syncthreads();
#pragma unroll
    for (int k = 0; k < 4; ++k)
        out[(size_t)(c0 + ty + 8 * k) * ldout + r0 + tx] = tl[tx][ty + 8 * k];
}

// ---------------------------------------------------------------------------
// Single-pass selective scan (R10 config, measured 378us / FETCH 97MB /
// WRITE 66MB / VALUBusy 74%): ONE WAVE per (b,d); 8 waves/block sharing one
// batch's packed B/C via double-buffered 32-step LDS windows.
//   R11 post-mortem (REVERTED): WSTEPS=16 halved the per-window y-write to
//   64B (partial TCC line) -> WRITE 66->139MB, scan 378->463. The 32-step
//   window is load-bearing: 32 consecutive y floats = 128B full line.
//   Occupancy-slack theory also refuted (38->36% with 6-block capacity).
//   Techniques in force: shared-B/C LDS staging (R6), dtx premult (R8),
//   b128 packed B/C reads (R9), v_pk f32 packing (R10), permlane32/16
//   folds + DPP quad_perm butterflies.
// ---------------------------------------------------------------------------
#define SCHUNK 512
#define WSTEPS 32     // B/C window

#if __has_builtin(__builtin_amdgcn_permlane32_swap)
#define HAVE_PL32 1
#endif
#if __has_builtin(__builtin_amdgcn_permlane16_swap)
#define HAVE_PL16 1
#endif

// Packed fold stage 1 (xor32): pr2[i] (t=2i,2i+1) folded with pr2[i+4] (t+8).
// Per component: identical to R5-verified pl32_fold(x,y) = r.x + r.y.
#ifdef HAVE_PL32
#define FOLD_S1_PK                                                           \
    _Pragma("unroll")                                                        \
    for (int i = 0; i < 4; ++i) {                                            \
        f32x2_t xx = dir32 ? pr2[i + 4] : pr2[i];                            \
        f32x2_t yy = dir32 ? pr2[i] : pr2[i + 4];                            \
        u32x2_t ra = __builtin_amdgcn_permlane32_swap(                       \
            __float_as_uint(xx.x), __float_as_uint(yy.x), false, false);     \
        u32x2_t rb = __builtin_amdgcn_permlane32_swap(                       \
            __float_as_uint(xx.y), __float_as_uint(yy.y), false, false);     \
        f32x2_t va = {__uint_as_float(ra.x), __uint_as_float(rb.x)};         \
        f32x2_t vb = {__uint_as_float(ra.y), __uint_as_float(rb.y)};         \
        pr2[i] = va + vb;                                                    \
    }
#else
#define FOLD_S1_PK                                                           \
    _Pragma("unroll")                                                        \
    for (int i = 0; i < 4; ++i) {                                            \
        _Pragma("unroll")                                                    \
        for (int u = 0; u < 2; ++u) {                                        \
            float p0 = u ? pr2[i].y : pr2[i].x;                              \
            float p8 = u ? pr2[i + 4].y : pr2[i + 4].x;                      \
            float send = (lane & 32) ? p0 : p8;                              \
            float recv = __shfl_xor(send, 32);                               \
            float res = ((lane & 32) ? p8 : p0) + recv;                      \
            if (u) pr2[i].y = res; else pr2[i].x = res;                      \
        }                                                                    \
    }
#endif

// Packed fold stage 2 (xor16): pr2[i] folded with pr2[i+2], i<2.
#ifdef HAVE_PL16
#define FOLD_S2_PK                                                           \
    _Pragma("unroll")                                                        \
    for (int i = 0; i < 2; ++i) {                                            \
        f32x2_t xx = dir16 ? pr2[i + 2] : pr2[i];                            \
        f32x2_t yy = dir16 ? pr2[i] : pr2[i + 2];                            \
        u32x2_t ra = __builtin_amdgcn_permlane16_swap(                       \
            __float_as_uint(xx.x), __float_as_uint(yy.x), false, false);     \
        u32x2_t rb = __builtin_amdgcn_permlane16_swap(                       \
            __float_as_uint(xx.y), __float_as_uint(yy.y), false, false);     \
        f32x2_t va = {__uint_as_float(ra.x), __uint_as_float(rb.x)};         \
        f32x2_t vb = {__uint_as_float(ra.y), __uint_as_float(rb.y)};         \
        pr2[i] = va + vb;                                                    \
    }
#else
#define FOLD_S2_PK                                                           \
    _Pragma("unroll")                                                        \
    for (int i = 0; i < 2; ++i) {                                            \
        _Pragma("unroll")                                                    \
        for (int u = 0; u < 2; ++u) {                                        \
            float p0 = u ? pr2[i].y : pr2[i].x;                              \
            float p4 = u ? pr2[i + 2].y : pr2[i + 2].x;                      \
            float send = (lane & 16) ? p0 : p4;                              \
            float recv = __shfl_xor(send, 16);                               \
            float res = ((lane & 16) ? p4 : p0) + recv;                      \
            if (u) pr2[i].y = res; else pr2[i].x = res;                      \
        }                                                                    \
    }
#endif

// xor2 then xor1 butterfly on V: DPP quad_perm (stays within quads).
#if __has_builtin(__builtin_amdgcn_mov_dpp)
#define BFLY21(V)                                                            \
    V += __int_as_float(__builtin_amdgcn_mov_dpp(                            \
             __float_as_int(V), 0x4E, 0xF, 0xF, true));                      \
    V += __int_as_float(__builtin_amdgcn_mov_dpp(                            \
             __float_as_int(V), 0xB1, 0xF, 0xF, true));
#else
#define BFLY21(V)                                                            \
    V += __shfl_xor(V, 2);                                                   \
    V += __shfl_xor(V, 1);
#endif

// Cooperative async stage of window W's packed B/C (16KB linear) into
// s_bc2[DB]. Each wave copies 2x 1KB (64 lanes x 16B); global src per-lane,
// LDS dest wave-uniform base (+lane*16 by HW).
#define STAGE_BC(W, DB)                                                      \
{                                                                            \
    const float* wbase_ = bc2 + (size_t)(bQ + 8u * (unsigned)(W)) * 512;     \
    _Pragma("unroll")                                                        \
    for (int r_ = 0; r_ < 2; ++r_) {                                         \
        const float* src_ = wbase_ + (wid * 2 + r_) * 256 + lane * 4;        \
        __builtin_amdgcn_global_load_lds((const AS1 void*)src_,              \
            (AS3 void*)&s_bc2[DB][(wid * 2 + r_) * 256], 16, 0, 0);          \
    }                                                                        \
}

#define GROUP16(GG2, ZV)                                                     \
{                                                                            \
    const int gp = gpos + (GG2);        /* step base within chunk */         \
    const int t4b = (GG2) >> 2;                                              \
    f32x4_t bv4[4], cv4[4];                                                  \
    _Pragma("unroll")                                                        \
    for (int a = 0; a < 4; ++a) {       /* b128: 4 steps' B (or C) per read */\
        bv4[a] = *(const f32x4_t*)&sbcw[(t4b + a) * 512 + lane * 4];         \
        cv4[a] = *(const f32x4_t*)&sbcw[(t4b + a) * 512 + 256 + lane * 4];   \
    }                                                                        \
    f32x4_t d44[4], x44[4];                                                  \
    d44[0] = *(const f32x4_t*)&sdt[gp];                                      \
    d44[1] = *(const f32x4_t*)&sdt[gp + 4];                                  \
    d44[2] = *(const f32x4_t*)&sdt[gp + 8];                                  \
    d44[3] = *(const f32x4_t*)&sdt[gp + 12];                                 \
    x44[0] = *(const f32x4_t*)&sdtx[gp];                                     \
    x44[1] = *(const f32x4_t*)&sdtx[gp + 4];                                 \
    x44[2] = *(const f32x4_t*)&sdtx[gp + 8];                                 \
    x44[3] = *(const f32x4_t*)&sdtx[gp + 12];                                \
    f32x2_t e2[8], ib2[8], cvp[8];                                           \
    _Pragma("unroll")                                                        \
    for (int a = 0; a < 4; ++a) {       /* packed muls: v_pk_mul_f32 */      \
        e2[2*a]    = __builtin_shufflevector(d44[a], d44[a], 0, 1) * An2v;   \
        e2[2*a+1]  = __builtin_shufflevector(d44[a], d44[a], 2, 3) * An2v;   \
        ib2[2*a]   = __builtin_shufflevector(x44[a], x44[a], 0, 1)           \
                   * __builtin_shufflevector(bv4[a], bv4[a], 0, 1);          \
        ib2[2*a+1] = __builtin_shufflevector(x44[a], x44[a], 2, 3)           \
                   * __builtin_shufflevector(bv4[a], bv4[a], 2, 3);          \
        cvp[2*a]   = __builtin_shufflevector(cv4[a], cv4[a], 0, 1);          \
        cvp[2*a+1] = __builtin_shufflevector(cv4[a], cv4[a], 2, 3);          \
    }                                                                        \
    f32x2_t pr2[8];                                                          \
    _Pragma("unroll")                                                        \
    for (int i = 0; i < 8; ++i) {       /* serial h chain; packed h*C */     \
        float a0 = __builtin_amdgcn_exp2f(e2[i].x);                          \
        float a1 = __builtin_amdgcn_exp2f(e2[i].y);                          \
        f32x2_t hh;                                                          \
        h = fmaf(h, a0, ib2[i].x); hh.x = h;                                 \
        h = fmaf(h, a1, ib2[i].y); hh.y = h;                                 \
        pr2[i] = hh * cvp[i];                                                \
    }                                                                        \
    FOLD_S1_PK;                                                              \
    FOLD_S2_PK;                                                              \
    float prr[4] = {pr2[0].x, pr2[0].y, pr2[1].x, pr2[1].y};                 \
    _Pragma("unroll")                                                        \
    for (int t = 0; t < 2; ++t) {       /* fold xor8: 4 -> 2 */              \
        float send = (lane & 8) ? prr[t] : prr[t + 2];                       \
        float recv = __shfl_xor(send, 8);                                    \
        prr[t] = ((lane & 8) ? prr[t + 2] : prr[t]) + recv;                  \
    }                                                                        \
    {                                   /* fold xor4: 2 -> 1 */              \
        float send = (lane & 4) ? prr[0] : prr[1];                           \
        float recv = __shfl_xor(send, 4);                                    \
        prr[0] = ((lane & 4) ? prr[1] : prr[0]) + recv;                      \
    }                                                                        \
    BFLY21(prr[0]);                     /* butterfly over 4 n-residues */    \
    if ((lane & 3) == 0) {              /* 16 writer lanes, step (lane>>2)&15 */ \
        float xv = bf2f(sx[gp + myt16]);                                     \
        zrow[cbase + gp + myt16] = fmaf(Dd, xv, prr[0]) * (ZV);              \
    }                                                                        \
}

__global__ __launch_bounds__(512, 4) void scan_seq_kernel(
    const float* __restrict__ dtT,           // [2048][8192] fp32
    const unsigned short* __restrict__ xcT16,// [2048][8192] bf16
    const float* __restrict__ bc2,           // [2048][128][4] packed B/C
    float* __restrict__ zyT,                 // [2048][8192]: silu(z) in, y out
    const float* __restrict__ A_log,         // [2048][64]
    const float* __restrict__ Dp)            // [2048]
{
    __shared__ __align__(16) float s_dt[8][SCHUNK];           // 16 KB
    __shared__ __align__(16) float s_dtx[8][SCHUNK];          // 16 KB
    __shared__ __align__(16) unsigned short s_x[8][SCHUNK];   // 8 KB
    __shared__ __align__(16) float s_bc2[2][WSTEPS * 128];    // 32 KB (packed B/C)
    // 72 KB/block -> 2 blocks/CU, 16 waves/CU, 512 blocks = 1 round

    const int tid  = threadIdx.x;
    const int wid  = tid >> 6;              // 0..7
    const int lane = tid & 63;
    const int bi   = blockIdx.x;            // 0..511; bi&1 constant per XCD
    const int b    = bi & 1;                // all 8 waves share b -> shared B/C
    const int d    = (bi >> 1) * 8 + wid;
    const unsigned bQ = (unsigned)b * (L_SEQ / 4);   // t4 offset of this batch

    const size_t rowbase = (size_t)d * BL + (size_t)(b * L_SEQ);
    const float An2 = -__expf(A_log[d * D_STATE + lane]) * 1.44269504f;
    const f32x2_t An2v = {An2, An2};
    const float Dd  = Dp[d];

    // permlane swap-direction probes (uniform, once; HW-verified in R5)
#ifdef HAVE_PL32
    bool dir32;
    {
        u32x2_t r = __builtin_amdgcn_permlane32_swap((unsigned)lane,
                        (unsigned)lane + 1000u, false, false);
        dir32 = (__builtin_amdgcn_readfirstlane(r.x) == 1032u);
    }
#endif
#ifdef HAVE_PL16
    bool dir16;
    {
        u32x2_t r = __builtin_amdgcn_permlane16_swap((unsigned)lane,
                        (unsigned)lane + 1000u, false, false);
        dir16 = (__builtin_amdgcn_readfirstlane(r.x) == 1016u);
    }
#endif

    float* sdt = s_dt[wid];
    float* sdtx = s_dtx[wid];
    unsigned short* sx = s_x[wid];
    const float* dtrow = dtT + rowbase;
    const unsigned short* xrow = xcT16 + rowbase;
    float* zrow = zyT + rowbase;
    const int myt16 = (lane >> 2) & 15;     // step index this lane ends up with

    // prefetch chunk 0. dt loaded in the SAME element range as x (8 elems
    // per lane): pA = elems 8*lane..+3, pB = 8*lane+4..+7, pX = 8 bf16.
    float4 pA = ((const float4*)dtrow)[2 * lane];
    float4 pB = ((const float4*)dtrow)[2 * lane + 1];
    uint4  pX = ((const uint4*)xrow)[lane];

    float h = 0.f;
    int buf = 0;

    STAGE_BC(0, 0);                          // prologue: window 0 -> buf 0
    __syncthreads();

    for (int c = 0; c < L_SEQ / SCHUNK; ++c) {
        // stage current chunk's dt/x/dtx to this wave's private LDS slice.
        // dtx = dt*x computed ONCE here (amortized over 32 groups).
        ((float4*)sdt)[2 * lane]     = pA;
        ((float4*)sdt)[2 * lane + 1] = pB;
        ((uint4*)sx)[lane]           = pX;
        float4 dxA, dxB;
        dxA.x = pA.x * __uint_as_float(pX.x << 16);
        dxA.y = pA.y * __uint_as_float(pX.x & 0xffff0000u);
        dxA.z = pA.z * __uint_as_float(pX.y << 16);
        dxA.w = pA.w * __uint_as_float(pX.y & 0xffff0000u);
        dxB.x = pB.x * __uint_as_float(pX.z << 16);
        dxB.y = pB.y * __uint_as_float(pX.z & 0xffff0000u);
        dxB.z = pB.z * __uint_as_float(pX.w << 16);
        dxB.w = pB.w * __uint_as_float(pX.w & 0xffff0000u);
        ((float4*)sdtx)[2 * lane]     = dxA;
        ((float4*)sdtx)[2 * lane + 1] = dxB;

        if (c < L_SEQ / SCHUNK - 1) {       // register-prefetch next chunk
            pA = ((const float4*)(dtrow + (c + 1) * SCHUNK))[2 * lane];
            pB = ((const float4*)(dtrow + (c + 1) * SCHUNK))[2 * lane + 1];
            pX = ((const uint4*)(xrow + (c + 1) * SCHUNK))[lane];
        }
        const int cbase = c * SCHUNK;

        for (int wd = 0; wd < SCHUNK / WSTEPS; ++wd) {
            const int wglob = c * (SCHUNK / WSTEPS) + wd;
            if (wglob + 1 < L_SEQ / WSTEPS)  // issue next window's staging EARLY
                STAGE_BC(wglob + 1, buf ^ 1);
            const int gpos = wd * WSTEPS;
            // hoist z for both groups: full-group latency cover
            float zv0 = 0.f, zv1 = 0.f;
            if ((lane & 3) == 0) {
                zv0 = zrow[cbase + gpos + myt16];
                zv1 = zrow[cbase + gpos + 16 + myt16];
            }
            const float* sbcw = s_bc2[buf];
            GROUP16(0, zv0);
            GROUP16(16, zv1);
            __syncthreads();                 // staging had a full window to land
            buf ^= 1;
        }
    }
}

// ---------------------------------------------------------------------------
extern "C" void kernel_launch(void* const* d_in, const int* in_sizes, int n_in,
                              void* d_out, int out_size, void* d_ws, size_t ws_size,
                              hipStream_t stream)
{
    const float* hs        = (const float*)d_in[0];  // [8192][1024]
    const float* in_proj_w = (const float*)d_in[1];  // [4096][1024]
    const float* conv_w    = (const float*)d_in[2];  // [2048][4]
    const float* conv_b    = (const float*)d_in[3];  // [2048]
    const float* x_proj_w  = (const float*)d_in[4];  // [256][2048]
    const float* dt_proj_w = (const float*)d_in[5];  // [2048][128]
    const float* dt_proj_b = (const float*)d_in[6];  // [2048]
    const float* A_log     = (const float*)d_in[7];  // [2048][64]
    const float* Dp        = (const float*)d_in[8];  // [2048]
    const float* out_proj_w= (const float*)d_in[9];  // [1024][2048]
    float* out = (float*)d_out;                      // [8192][1024]

    // workspace map (MiB offsets; peak ~177.5 MiB):
    //  S0 @0   : xT fp32 (64) -> xc16 bf16 (32) @0 -> dtT fp32 (64) @0
    //  S1 @64  : zT fp32 (64)  (scan writes y in place; merged GEMM writes
    //            rows 2048..4095 here: zT == xT + 2048*8192 floats)
    //  S2 @128 : W1_16 (8)@128 + hs16 (16)@136 -> xcT16 bf16 (32)@128 -> y16 (32)@128
    //  tail    : xdbl fp32 (8)@160, xdbl16 (2)@169 + bc2 (4)@169.5-ish region
    //            (xdbl16 at 169, bc2 at 169 reuses dead region -- xdbl16,
    //            Wx16, Wdt16 all dead by repack time), Wx16 (1)@171,
    //            Wdt16 (.5)@172, Wo16 (4)@173  (end 177)
    char* ws = (char*)d_ws;
    const size_t MiB = 1024 * 1024;
    float*          xT    = (float*)(ws);
    unsigned short* xc16  = (unsigned short*)(ws);
    float*          dtT   = (float*)(ws);
    float*          zT    = (float*)(ws + 64 * MiB);
    unsigned short* W1_16 = (unsigned short*)(ws + 128 * MiB);
    unsigned short* hs16  = (unsigned short*)(ws + 136 * MiB);
    unsigned short* xcT16 = (unsigned short*)(ws + 128 * MiB);
    unsigned short* y16   = (unsigned short*)(ws + 128 * MiB);
    float*          xdbl  = (float*)(ws + 160 * MiB);
    unsigned short* xdbl16= (unsigned short*)(ws + 169 * MiB);
    float*          bc2   = (float*)(ws + 169 * MiB + 2 * MiB);  // after xdbl16
    unsigned short* Wx16  = (unsigned short*)(ws + 171 * MiB + 4 * MiB);
    unsigned short* Wdt16 = (unsigned short*)(ws + 176 * MiB);
    unsigned short* Wo16  = (unsigned short*)(ws + 177 * MiB);

    dim3 blk(256);

    // bf16 conversions
    cvt_f32_bf16<<<8192, blk, 0, stream>>>(hs, hs16, 2097152);
    cvt_f32_bf16<<<4096, blk, 0, stream>>>(in_proj_w, W1_16, 1048576);
    cvt_f32_bf16<<<512, blk, 0, stream>>>(x_proj_w, Wx16, 131072);
    cvt_f32_bf16<<<256, blk, 0, stream>>>(dt_proj_w, Wdt16, 65536);
    cvt_f32_bf16<<<2048, blk, 0, stream>>>(out_proj_w, Wo16, 524288);

    // 1+2 merged) C[4096][8192] = W1 . hs^T; rows<2048 -> xT (no act),
    //             rows>=2048 -> zT (silu). zT == xT + 2048*8192 floats.
    gemm_bf16<<<dim3(64, 32), blk, 0, stream>>>(
        W1_16, D_MODEL, hs16, D_MODEL, xT, BL, D_MODEL, nullptr, 3);

    // 3) xcT16 = bf16(silu(conv(xT) + b))
    conv_silu_kernel<<<(D_INNER * (BL / 4)) / 256, blk, 0, stream>>>(
        xT, conv_w, conv_b, xcT16);

    // 4) xc16[m][d] = transpose(xcT16)
    transpose_bf16<<<dim3(BL / 32, D_INNER / 32), blk, 0, stream>>>(
        xcT16, BL, xc16, D_INNER);

    // 5) xdbl[m][256] = xc . x_proj^T   (M=8192, N=256, K=2048)
    gemm_bf16<<<dim3(2, 64), blk, 0, stream>>>(
        xc16, D_INNER, Wx16, D_INNER, xdbl, 256, D_INNER, nullptr, 0);

    // 6+7b merged) xdbl16 = bf16(xdbl[:, :128]); bc2 = packed B/C
    cvt_dt_repack<<<2048, blk, 0, stream>>>(xdbl, xdbl16, bc2);

    // 7) dtT[d][m] = softplus(Wdt . xdbl_dt^T + b[d])  (M=2048, N=8192, K=128)
    gemm_bf16<<<dim3(64, 16), blk, 0, stream>>>(
        Wdt16, DT_RANK, xdbl16, DT_RANK, dtT, BL, DT_RANK, dt_proj_b, 1);

    // 8) single-pass scan: 1 wave per (b,d), 8 waves/block, packed B/C LDS
    scan_seq_kernel<<<512, dim3(512), 0, stream>>>(
        dtT, xcT16, bc2, zT, A_log, Dp);

    // 9) y16[m][d] = bf16(transpose(zT))
    transpose_f32_bf16<<<dim3(BL / 32, D_INNER / 32), blk, 0, stream>>>(
        zT, BL, y16, D_INNER);

    // 10) out = y . out_proj^T   (M=8192, N=1024, K=2048)
    gemm_bf16<<<dim3(8, 64), blk, 0, stream>>>(
        y16, D_INNER, Wo16, D_INNER, out, D_MODEL, D_INNER, nullptr, 0);
}

// Round 14
// 837.639 us; speedup vs baseline: 1.0731x; 1.0013x over previous
//
#include <hip/hip_runtime.h>
#include <math.h>

// Problem constants (fixed by the reference)
#define B_SZ 2
#define L_SEQ 4096
#define D_MODEL 1024
#define D_INNER 2048
#define D_STATE 64
#define DT_RANK 128
#define BL (B_SZ * L_SEQ)          // 8192 tokens

#define AS1 __attribute__((address_space(1)))
#define AS3 __attribute__((address_space(3)))

typedef __attribute__((ext_vector_type(8))) short bf16x8_t;  // 8 bf16 = 4 VGPRs
typedef __attribute__((ext_vector_type(4))) float f32x4_t;
typedef __attribute__((ext_vector_type(2))) float f32x2_t;
typedef __attribute__((ext_vector_type(2))) unsigned int u32x2_t;

__device__ __forceinline__ unsigned short f2bf(float f) {
    unsigned int u = __float_as_uint(f);
    u = (u + 0x7FFFu + ((u >> 16) & 1u)) >> 16;   // RNE
    return (unsigned short)u;
}
__device__ __forceinline__ float bf2f(unsigned short h) {
    return __uint_as_float(((unsigned int)h) << 16);
}

// ---------------------------------------------------------------------------
// fp32 -> bf16 bulk convert (n4 = count of float4 groups)
// ---------------------------------------------------------------------------
__global__ __launch_bounds__(256) void cvt_f32_bf16(
    const float* __restrict__ in, unsigned short* __restrict__ out, int n4)
{
    int i = blockIdx.x * 256 + threadIdx.x;
    if (i >= n4) return;
    float4 v = ((const float4*)in)[i];
    ushort4 o;
    o.x = f2bf(v.x); o.y = f2bf(v.y); o.z = f2bf(v.z); o.w = f2bf(v.w);
    ((ushort4*)out)[i] = o;
}

// xdbl[:, :128] (fp32, row stride 256) -> packed bf16 [8192][128]
__global__ __launch_bounds__(256) void cvt_dtpart(
    const float* __restrict__ xdbl, unsigned short* __restrict__ out)
{
    int i = blockIdx.x * 256 + threadIdx.x;   // 0 .. 8192*32-1
    int m = i >> 5, c = i & 31;
    float4 v = *(const float4*)(xdbl + (size_t)m * 256 + c * 4);
    ushort4 o;
    o.x = f2bf(v.x); o.y = f2bf(v.y); o.z = f2bf(v.z); o.w = f2bf(v.w);
    ((ushort4*)(out))[(size_t)m * 32 + c] = o;
}

// B/C repack: bc2[t>>2][n][t&3] = xdbl[t][128+n]  (n=0..127; B at n<64, C at
// n>=64). Makes 4 consecutive steps' B (or C) for one lane a contiguous 16B
// quad -> scan reads b128 instead of 4x b32. 4MB r + 4MB w, ~4us.
__global__ __launch_bounds__(256) void repack_bc(
    const float* __restrict__ xdbl,   // [8192][256]
    float* __restrict__ bc2)          // [2048][128][4]
{
    int i = blockIdx.x * 256 + threadIdx.x;   // 0 .. 262143
    int t4 = i >> 7, n = i & 127;
    const float* s = xdbl + (size_t)(t4 * 4) * 256 + 128 + n;
    float4 o;
    o.x = s[0]; o.y = s[256]; o.z = s[512]; o.w = s[768];
    ((float4*)bc2)[i] = o;
}

// ---------------------------------------------------------------------------
// bf16 MFMA GEMM: C[m][n] = act( sum_k A[m][k]*B[n][k] [+ bias[m]] )
// act: 0 none, 1 softplus (bias by row), 2 silu.
// R13: XCD-aware block swizzle (T1): the HW round-robins linear blockIdx
// across the 8 XCDs; remap so logically-consecutive tiles (which share the
// same A row-panel) co-locate on one XCD -> A-panel fetched once per XCD
// instead of 8x. Bijective since every grid here has nwg % 8 == 0.
// ---------------------------------------------------------------------------
__global__ __launch_bounds__(256) void gemm_bf16(
    const unsigned short* __restrict__ A, int lda,
    const unsigned short* __restrict__ B, int ldb,
    float* __restrict__ C, int ldc, int K,
    const float* __restrict__ bias, int act)
{
    __shared__ unsigned short As[128 * 32];   // [row][k] linear, no pad
    __shared__ unsigned short Bs[128 * 32];

    const int tid = threadIdx.x;
    const int w = tid >> 6, lane = tid & 63;

    // T1 XCD swizzle (nwg % 8 == 0 for all call sites)
    const int nwg = gridDim.x * gridDim.y;
    int orig = blockIdx.y * gridDim.x + blockIdx.x;
    int logical = orig;
    if ((nwg & 7) == 0) {
        int q = nwg >> 3;
        logical = (orig & 7) * q + (orig >> 3);
    }
    const int bx = logical % gridDim.x;
    const int by = logical / gridDim.x;
    const int bm = by * 128, bn = bx * 128;
    const int wm = (w & 1) * 64, wn = (w >> 1) * 64;

    f32x4_t acc[4][4];
#pragma unroll
    for (int i = 0; i < 4; ++i)
#pragma unroll
        for (int j = 0; j < 4; ++j) acc[i][j] = (f32x4_t){0.f, 0.f, 0.f, 0.f};

    const int srow = lane >> 2;
    const int scol = (lane & 3) * 8;
    const unsigned short* Ag0 = A + (size_t)(bm + w * 16 + srow) * lda + scol;
    const unsigned short* Ag1 = A + (size_t)(bm + 64 + w * 16 + srow) * lda + scol;
    const unsigned short* Bg0 = B + (size_t)(bn + w * 16 + srow) * ldb + scol;
    const unsigned short* Bg1 = B + (size_t)(bn + 64 + w * 16 + srow) * ldb + scol;
    unsigned short* la0 = &As[(w * 16) * 32];
    unsigned short* la1 = &As[(64 + w * 16) * 32];
    unsigned short* lb0 = &Bs[(w * 16) * 32];
    unsigned short* lb1 = &Bs[(64 + w * 16) * 32];

    const int fr = lane & 15;
    const int fk = (lane >> 4) * 8;

    for (int k0 = 0; k0 < K; k0 += 32) {
        __syncthreads();
        __builtin_amdgcn_global_load_lds((const AS1 void*)(Ag0 + k0), (AS3 void*)la0, 16, 0, 0);
        __builtin_amdgcn_global_load_lds((const AS1 void*)(Ag1 + k0), (AS3 void*)la1, 16, 0, 0);
        __builtin_amdgcn_global_load_lds((const AS1 void*)(Bg0 + k0), (AS3 void*)lb0, 16, 0, 0);
        __builtin_amdgcn_global_load_lds((const AS1 void*)(Bg1 + k0), (AS3 void*)lb1, 16, 0, 0);
        __syncthreads();

        bf16x8_t af[4], bfr[4];
#pragma unroll
        for (int i = 0; i < 4; ++i)
            af[i] = *(const bf16x8_t*)&As[(wm + i * 16 + fr) * 32 + fk];
#pragma unroll
        for (int j = 0; j < 4; ++j)
            bfr[j] = *(const bf16x8_t*)&Bs[(wn + j * 16 + fr) * 32 + fk];
#pragma unroll
        for (int i = 0; i < 4; ++i)
#pragma unroll
            for (int j = 0; j < 4; ++j)
                acc[i][j] = __builtin_amdgcn_mfma_f32_16x16x32_bf16(
                    af[i], bfr[j], acc[i][j], 0, 0, 0);
    }

    const int erow = (lane >> 4) * 4;
    const int ecol = lane & 15;
#pragma unroll
    for (int i = 0; i < 4; ++i) {
        int gr0 = bm + wm + i * 16 + erow;
#pragma unroll
        for (int j = 0; j < 4; ++j) {
            int gc = bn + wn + j * 16 + ecol;
#pragma unroll
            for (int r = 0; r < 4; ++r) {
                float v = acc[i][j][r];
                if (act == 1) {
                    float t = v + bias[gr0 + r];
                    v = (t > 20.f) ? t : log1pf(__expf(t));
                } else if (act == 2) {
                    v = v / (1.f + __expf(-v));
                }
                C[(size_t)(gr0 + r) * ldc + gc] = v;
            }
        }
    }
}

// ---------------------------------------------------------------------------
// causal depthwise conv (k=4) + bias + silu on [d][m] layout, bf16 output.
// ---------------------------------------------------------------------------
__global__ __launch_bounds__(256) void conv_silu_kernel(
    const float* __restrict__ xT,     // [2048][8192] fp32
    const float* __restrict__ w,      // [2048][4]
    const float* __restrict__ bias,   // [2048]
    unsigned short* __restrict__ xcT16) // [2048][8192] bf16
{
    int gid = blockIdx.x * blockDim.x + threadIdx.x;  // 0 .. 2048*2048-1
    int d = gid >> 11;
    int c4 = gid & 2047;
    int m0 = c4 * 4;
    int l0 = m0 & (L_SEQ - 1);

    const float* row = xT + (size_t)d * BL;
    float4 v = *(const float4*)(row + m0);
    float4 p;
    if (l0 == 0) { p.x = p.y = p.z = p.w = 0.f; }
    else         { p = *(const float4*)(row + m0 - 4); }

    float4 wv = ((const float4*)w)[d];
    float bb = bias[d];
    float e[4];
    e[0] = bb + wv.x * p.y + wv.y * p.z + wv.z * p.w + wv.w * v.x;
    e[1] = bb + wv.x * p.z + wv.y * p.w + wv.z * v.x + wv.w * v.y;
    e[2] = bb + wv.x * p.w + wv.y * v.x + wv.z * v.y + wv.w * v.z;
    e[3] = bb + wv.x * v.x + wv.y * v.y + wv.z * v.z + wv.w * v.w;
    ushort4 o;
    o.x = f2bf(e[0] / (1.f + __expf(-e[0])));
    o.y = f2bf(e[1] / (1.f + __expf(-e[1])));
    o.z = f2bf(e[2] / (1.f + __expf(-e[2])));
    o.w = f2bf(e[3] / (1.f + __expf(-e[3])));
    ((ushort4*)(xcT16 + (size_t)d * BL))[c4] = o;
}

// ---------------------------------------------------------------------------
// 32x32 tiled transposes (coalesced both sides)
// ---------------------------------------------------------------------------
__global__ __launch_bounds__(256) void transpose_f32_bf16(
    const float* __restrict__ in, int ldin,
    unsigned short* __restrict__ out, int ldout)
{
    __shared__ float tl[32][33];
    int r0 = blockIdx.y * 32, c0 = blockIdx.x * 32;
    int tx = threadIdx.x & 31, ty = threadIdx.x >> 5;
#pragma unroll
    for (int k = 0; k < 4; ++k)
        tl[ty + 8 * k][tx] = in[(size_t)(r0 + ty + 8 * k) * ldin + c0 + tx];
    __syncthreads();
#pragma unroll
    for (int k = 0; k < 4; ++k)
        out[(size_t)(c0 + ty + 8 * k) * ldout + r0 + tx] = f2bf(tl[tx][ty + 8 * k]);
}

__global__ __launch_bounds__(256) void transpose_bf16(
    const unsigned short* __restrict__ in, int ldin,
    unsigned short* __restrict__ out, int ldout)
{
    __shared__ unsigned short tl[32][33];
    int r0 = blockIdx.y * 32, c0 = blockIdx.x * 32;
    int tx = threadIdx.x & 31, ty = threadIdx.x >> 5;
#pragma unroll
    for (int k = 0; k < 4; ++k)
        tl[ty + 8 * k][tx] = in[(size_t)(r0 + ty + 8 * k) * ldin + c0 + tx];
    __syncthreads();
#pragma unroll
    for (int k = 0; k < 4; ++k)
        out[(size_t)(c0 + ty + 8 * k) * ldout + r0 + tx] = tl[tx][ty + 8 * k];
}

// ---------------------------------------------------------------------------
// Single-pass selective scan (R10 config, re-measured R12: 378us / FETCH
// 97MB / WRITE 66MB / VALUBusy 74%): ONE WAVE per (b,d); 8 waves/block
// sharing one batch's packed B/C via double-buffered 32-step LDS windows.
//   WSTEPS=32 is load-bearing (R11: 16-step windows -> partial-line y
//   writes -> WRITE 139MB, +85us). Techniques: shared-B/C LDS staging (R6),
//   dtx premult (R8), b128 packed B/C reads (R9), v_pk f32 packing (R10),
//   permlane32/16 folds + DPP quad_perm butterflies.
//   VALU audit: ~77 VALU instr/group x 2cy x 4 waves ~= 616 of 886
//   cy/group budget = the measured 74% VALUBusy -> near issue floor.
// ---------------------------------------------------------------------------
#define SCHUNK 512
#define WSTEPS 32     // B/C window

#if __has_builtin(__builtin_amdgcn_permlane32_swap)
#define HAVE_PL32 1
#endif
#if __has_builtin(__builtin_amdgcn_permlane16_swap)
#define HAVE_PL16 1
#endif

// Packed fold stage 1 (xor32): pr2[i] (t=2i,2i+1) folded with pr2[i+4] (t+8).
// Per component: identical to R5-verified pl32_fold(x,y) = r.x + r.y.
#ifdef HAVE_PL32
#define FOLD_S1_PK                                                           \
    _Pragma("unroll")                                                        \
    for (int i = 0; i < 4; ++i) {                                            \
        f32x2_t xx = dir32 ? pr2[i + 4] : pr2[i];                            \
        f32x2_t yy = dir32 ? pr2[i] : pr2[i + 4];                            \
        u32x2_t ra = __builtin_amdgcn_permlane32_swap(                       \
            __float_as_uint(xx.x), __float_as_uint(yy.x), false, false);     \
        u32x2_t rb = __builtin_amdgcn_permlane32_swap(                       \
            __float_as_uint(xx.y), __float_as_uint(yy.y), false, false);     \
        f32x2_t va = {__uint_as_float(ra.x), __uint_as_float(rb.x)};         \
        f32x2_t vb = {__uint_as_float(ra.y), __uint_as_float(rb.y)};         \
        pr2[i] = va + vb;                                                    \
    }
#else
#define FOLD_S1_PK                                                           \
    _Pragma("unroll")                                                        \
    for (int i = 0; i < 4; ++i) {                                            \
        _Pragma("unroll")                                                    \
        for (int u = 0; u < 2; ++u) {                                        \
            float p0 = u ? pr2[i].y : pr2[i].x;                              \
            float p8 = u ? pr2[i + 4].y : pr2[i + 4].x;                      \
            float send = (lane & 32) ? p0 : p8;                              \
            float recv = __shfl_xor(send, 32);                               \
            float res = ((lane & 32) ? p8 : p0) + recv;                      \
            if (u) pr2[i].y = res; else pr2[i].x = res;                      \
        }                                                                    \
    }
#endif

// Packed fold stage 2 (xor16): pr2[i] folded with pr2[i+2], i<2.
#ifdef HAVE_PL16
#define FOLD_S2_PK                                                           \
    _Pragma("unroll")                                                        \
    for (int i = 0; i < 2; ++i) {                                            \
        f32x2_t xx = dir16 ? pr2[i + 2] : pr2[i];                            \
        f32x2_t yy = dir16 ? pr2[i] : pr2[i + 2];                            \
        u32x2_t ra = __builtin_amdgcn_permlane16_swap(                       \
            __float_as_uint(xx.x), __float_as_uint(yy.x), false, false);     \
        u32x2_t rb = __builtin_amdgcn_permlane16_swap(                       \
            __float_as_uint(xx.y), __float_as_uint(yy.y), false, false);     \
        f32x2_t va = {__uint_as_float(ra.x), __uint_as_float(rb.x)};         \
        f32x2_t vb = {__uint_as_float(ra.y), __uint_as_float(rb.y)};         \
        pr2[i] = va + vb;                                                    \
    }
#else
#define FOLD_S2_PK                                                           \
    _Pragma("unroll")                                                        \
    for (int i = 0; i < 2; ++i) {                                            \
        _Pragma("unroll")                                                    \
        for (int u = 0; u < 2; ++u) {                                        \
            float p0 = u ? pr2[i].y : pr2[i].x;                              \
            float p4 = u ? pr2[i + 2].y : pr2[i + 2].x;                      \
            float send = (lane & 16) ? p0 : p4;                              \
            float recv = __shfl_xor(send, 16);                               \
            float res = ((lane & 16) ? p4 : p0) + recv;                      \
            if (u) pr2[i].y = res; else pr2[i].x = res;                      \
        }                                                                    \
    }
#endif

// xor2 then xor1 butterfly on V: DPP quad_perm (stays within quads).
#if __has_builtin(__builtin_amdgcn_mov_dpp)
#define BFLY21(V)                                                            \
    V += __int_as_float(__builtin_amdgcn_mov_dpp(                            \
             __float_as_int(V), 0x4E, 0xF, 0xF, true));                      \
    V += __int_as_float(__builtin_amdgcn_mov_dpp(                            \
             __float_as_int(V), 0xB1, 0xF, 0xF, true));
#else
#define BFLY21(V)                                                            \
    V += __shfl_xor(V, 2);                                                   \
    V += __shfl_xor(V, 1);
#endif

// Cooperative async stage of window W's packed B/C (16KB linear) into
// s_bc2[DB]. Each wave copies 2x 1KB (64 lanes x 16B); global src per-lane,
// LDS dest wave-uniform base (+lane*16 by HW).
#define STAGE_BC(W, DB)                                                      \
{                                                                            \
    const float* wbase_ = bc2 + (size_t)(bQ + 8u * (unsigned)(W)) * 512;     \
    _Pragma("unroll")                                                        \
    for (int r_ = 0; r_ < 2; ++r_) {                                         \
        const float* src_ = wbase_ + (wid * 2 + r_) * 256 + lane * 4;        \
        __builtin_amdgcn_global_load_lds((const AS1 void*)src_,              \
            (AS3 void*)&s_bc2[DB][(wid * 2 + r_) * 256], 16, 0, 0);          \
    }                                                                        \
}

#define GROUP16(GG2, ZV)                                                     \
{                                                                            \
    const int gp = gpos + (GG2);        /* step base within chunk */         \
    const int t4b = (GG2) >> 2;                                              \
    f32x4_t bv4[4], cv4[4];                                                  \
    _Pragma("unroll")                                                        \
    for (int a = 0; a < 4; ++a) {       /* b128: 4 steps' B (or C) per read */\
        bv4[a] = *(const f32x4_t*)&sbcw[(t4b + a) * 512 + lane * 4];         \
        cv4[a] = *(const f32x4_t*)&sbcw[(t4b + a) * 512 + 256 + lane * 4];   \
    }                                                                        \
    f32x4_t d44[4], x44[4];                                                  \
    d44[0] = *(const f32x4_t*)&sdt[gp];                                      \
    d44[1] = *(const f32x4_t*)&sdt[gp + 4];                                  \
    d44[2] = *(const f32x4_t*)&sdt[gp + 8];                                  \
    d44[3] = *(const f32x4_t*)&sdt[gp + 12];                                 \
    x44[0] = *(const f32x4_t*)&sdtx[gp];                                     \
    x44[1] = *(const f32x4_t*)&sdtx[gp + 4];                                 \
    x44[2] = *(const f32x4_t*)&sdtx[gp + 8];                                 \
    x44[3] = *(const f32x4_t*)&sdtx[gp + 12];                                \
    f32x2_t e2[8], ib2[8], cvp[8];                                           \
    _Pragma("unroll")                                                        \
    for (int a = 0; a < 4; ++a) {       /* packed muls: v_pk_mul_f32 */      \
        e2[2*a]    = __builtin_shufflevector(d44[a], d44[a], 0, 1) * An2v;   \
        e2[2*a+1]  = __builtin_shufflevector(d44[a], d44[a], 2, 3) * An2v;   \
        ib2[2*a]   = __builtin_shufflevector(x44[a], x44[a], 0, 1)           \
                   * __builtin_shufflevector(bv4[a], bv4[a], 0, 1);          \
        ib2[2*a+1] = __builtin_shufflevector(x44[a], x44[a], 2, 3)           \
                   * __builtin_shufflevector(bv4[a], bv4[a], 2, 3);          \
        cvp[2*a]   = __builtin_shufflevector(cv4[a], cv4[a], 0, 1);          \
        cvp[2*a+1] = __builtin_shufflevector(cv4[a], cv4[a], 2, 3);          \
    }                                                                        \
    f32x2_t pr2[8];                                                          \
    _Pragma("unroll")                                                        \
    for (int i = 0; i < 8; ++i) {       /* serial h chain; packed h*C */     \
        float a0 = __builtin_amdgcn_exp2f(e2[i].x);                          \
        float a1 = __builtin_amdgcn_exp2f(e2[i].y);                          \
        f32x2_t hh;                                                          \
        h = fmaf(h, a0, ib2[i].x); hh.x = h;                                 \
        h = fmaf(h, a1, ib2[i].y); hh.y = h;                                 \
        pr2[i] = hh * cvp[i];                                                \
    }                                                                        \
    FOLD_S1_PK;                                                              \
    FOLD_S2_PK;                                                              \
    float prr[4] = {pr2[0].x, pr2[0].y, pr2[1].x, pr2[1].y};                 \
    _Pragma("unroll")                                                        \
    for (int t = 0; t < 2; ++t) {       /* fold xor8: 4 -> 2 */              \
        float send = (lane & 8) ? prr[t] : prr[t + 2];                       \
        float recv = __shfl_xor(send, 8);                                    \
        prr[t] = ((lane & 8) ? prr[t + 2] : prr[t]) + recv;                  \
    }                                                                        \
    {                                   /* fold xor4: 2 -> 1 */              \
        float send = (lane & 4) ? prr[0] : prr[1];                           \
        float recv = __shfl_xor(send, 4);                                    \
        prr[0] = ((lane & 4) ? prr[1] : prr[0]) + recv;                      \
    }                                                                        \
    BFLY21(prr[0]);                     /* butterfly over 4 n-residues */    \
    if ((lane & 3) == 0) {              /* 16 writer lanes, step (lane>>2)&15 */ \
        float xv = bf2f(sx[gp + myt16]);                                     \
        zrow[cbase + gp + myt16] = fmaf(Dd, xv, prr[0]) * (ZV);              \
    }                                                                        \
}

__global__ __launch_bounds__(512, 4) void scan_seq_kernel(
    const float* __restrict__ dtT,           // [2048][8192] fp32
    const unsigned short* __restrict__ xcT16,// [2048][8192] bf16
    const float* __restrict__ bc2,           // [2048][128][4] packed B/C
    float* __restrict__ zyT,                 // [2048][8192]: silu(z) in, y out
    const float* __restrict__ A_log,         // [2048][64]
    const float* __restrict__ Dp)            // [2048]
{
    __shared__ __align__(16) float s_dt[8][SCHUNK];           // 16 KB
    __shared__ __align__(16) float s_dtx[8][SCHUNK];          // 16 KB
    __shared__ __align__(16) unsigned short s_x[8][SCHUNK];   // 8 KB
    __shared__ __align__(16) float s_bc2[2][WSTEPS * 128];    // 32 KB (packed B/C)
    // 72 KB/block -> 2 blocks/CU, 16 waves/CU, 512 blocks = 1 round

    const int tid  = threadIdx.x;
    const int wid  = tid >> 6;              // 0..7
    const int lane = tid & 63;
    const int bi   = blockIdx.x;            // 0..511; bi&1 constant per XCD
    const int b    = bi & 1;                // all 8 waves share b -> shared B/C
    const int d    = (bi >> 1) * 8 + wid;
    const unsigned bQ = (unsigned)b * (L_SEQ / 4);   // t4 offset of this batch

    const size_t rowbase = (size_t)d * BL + (size_t)(b * L_SEQ);
    const float An2 = -__expf(A_log[d * D_STATE + lane]) * 1.44269504f;
    const f32x2_t An2v = {An2, An2};
    const float Dd  = Dp[d];

    // permlane swap-direction probes (uniform, once; HW-verified in R5)
#ifdef HAVE_PL32
    bool dir32;
    {
        u32x2_t r = __builtin_amdgcn_permlane32_swap((unsigned)lane,
                        (unsigned)lane + 1000u, false, false);
        dir32 = (__builtin_amdgcn_readfirstlane(r.x) == 1032u);
    }
#endif
#ifdef HAVE_PL16
    bool dir16;
    {
        u32x2_t r = __builtin_amdgcn_permlane16_swap((unsigned)lane,
                        (unsigned)lane + 1000u, false, false);
        dir16 = (__builtin_amdgcn_readfirstlane(r.x) == 1016u);
    }
#endif

    float* sdt = s_dt[wid];
    float* sdtx = s_dtx[wid];
    unsigned short* sx = s_x[wid];
    const float* dtrow = dtT + rowbase;
    const unsigned short* xrow = xcT16 + rowbase;
    float* zrow = zyT + rowbase;
    const int myt16 = (lane >> 2) & 15;     // step index this lane ends up with

    // prefetch chunk 0. dt loaded in the SAME element range as x (8 elems
    // per lane): pA = elems 8*lane..+3, pB = 8*lane+4..+7, pX = 8 bf16.
    float4 pA = ((const float4*)dtrow)[2 * lane];
    float4 pB = ((const float4*)dtrow)[2 * lane + 1];
    uint4  pX = ((const uint4*)xrow)[lane];

    float h = 0.f;
    int buf = 0;

    STAGE_BC(0, 0);                          // prologue: window 0 -> buf 0
    __syncthreads();

    for (int c = 0; c < L_SEQ / SCHUNK; ++c) {
        // stage current chunk's dt/x/dtx to this wave's private LDS slice.
        // dtx = dt*x computed ONCE here (amortized over 32 groups).
        ((float4*)sdt)[2 * lane]     = pA;
        ((float4*)sdt)[2 * lane + 1] = pB;
        ((uint4*)sx)[lane]           = pX;
        float4 dxA, dxB;
        dxA.x = pA.x * __uint_as_float(pX.x << 16);
        dxA.y = pA.y * __uint_as_float(pX.x & 0xffff0000u);
        dxA.z = pA.z * __uint_as_float(pX.y << 16);
        dxA.w = pA.w * __uint_as_float(pX.y & 0xffff0000u);
        dxB.x = pB.x * __uint_as_float(pX.z << 16);
        dxB.y = pB.y * __uint_as_float(pX.z & 0xffff0000u);
        dxB.z = pB.z * __uint_as_float(pX.w << 16);
        dxB.w = pB.w * __uint_as_float(pX.w & 0xffff0000u);
        ((float4*)sdtx)[2 * lane]     = dxA;
        ((float4*)sdtx)[2 * lane + 1] = dxB;

        if (c < L_SEQ / SCHUNK - 1) {       // register-prefetch next chunk
            pA = ((const float4*)(dtrow + (c + 1) * SCHUNK))[2 * lane];
            pB = ((const float4*)(dtrow + (c + 1) * SCHUNK))[2 * lane + 1];
            pX = ((const uint4*)(xrow + (c + 1) * SCHUNK))[lane];
        }
        const int cbase = c * SCHUNK;

        for (int wd = 0; wd < SCHUNK / WSTEPS; ++wd) {
            const int wglob = c * (SCHUNK / WSTEPS) + wd;
            if (wglob + 1 < L_SEQ / WSTEPS)  // issue next window's staging EARLY
                STAGE_BC(wglob + 1, buf ^ 1);
            const int gpos = wd * WSTEPS;
            // hoist z for both groups: full-group latency cover
            float zv0 = 0.f, zv1 = 0.f;
            if ((lane & 3) == 0) {
                zv0 = zrow[cbase + gpos + myt16];
                zv1 = zrow[cbase + gpos + 16 + myt16];
            }
            const float* sbcw = s_bc2[buf];
            GROUP16(0, zv0);
            GROUP16(16, zv1);
            __syncthreads();                 // staging had a full window to land
            buf ^= 1;
        }
    }
}

// ---------------------------------------------------------------------------
extern "C" void kernel_launch(void* const* d_in, const int* in_sizes, int n_in,
                              void* d_out, int out_size, void* d_ws, size_t ws_size,
                              hipStream_t stream)
{
    const float* hs        = (const float*)d_in[0];  // [8192][1024]
    const float* in_proj_w = (const float*)d_in[1];  // [4096][1024]
    const float* conv_w    = (const float*)d_in[2];  // [2048][4]
    const float* conv_b    = (const float*)d_in[3];  // [2048]
    const float* x_proj_w  = (const float*)d_in[4];  // [256][2048]
    const float* dt_proj_w = (const float*)d_in[5];  // [2048][128]
    const float* dt_proj_b = (const float*)d_in[6];  // [2048]
    const float* A_log     = (const float*)d_in[7];  // [2048][64]
    const float* Dp        = (const float*)d_in[8];  // [2048]
    const float* out_proj_w= (const float*)d_in[9];  // [1024][2048]
    float* out = (float*)d_out;                      // [8192][1024]

    // workspace map (MiB offsets; peak ~177.5 MiB) -- R10 layout restored:
    //  S0 @0   : xT fp32 (64) -> xc16 bf16 (32) @0 -> dtT fp32 (64) @0
    //  S1 @64  : zT fp32 (64)  (scan writes y in place)
    //  S2 @128 : W1_16 (8)@128 + hs16 (16)@136 -> xcT16 bf16 (32)@128 -> y16 (32)@128
    //  tail    : xdbl fp32 (8)@160, xdbl16 (2)@169 -> bc2 (4)@169 (xdbl16,
    //            Wx16, Wdt16 all dead by repack time), Wx16 (1)@171,
    //            Wdt16 (.5)@172, Wo16 (4)@173  (end 177)
    char* ws = (char*)d_ws;
    const size_t MiB = 1024 * 1024;
    float*          xT    = (float*)(ws);
    unsigned short* xc16  = (unsigned short*)(ws);
    float*          dtT   = (float*)(ws);
    float*          zT    = (float*)(ws + 64 * MiB);
    unsigned short* W1_16 = (unsigned short*)(ws + 128 * MiB);
    unsigned short* hs16  = (unsigned short*)(ws + 136 * MiB);
    unsigned short* xcT16 = (unsigned short*)(ws + 128 * MiB);
    unsigned short* y16   = (unsigned short*)(ws + 128 * MiB);
    float*          xdbl  = (float*)(ws + 160 * MiB);
    unsigned short* xdbl16= (unsigned short*)(ws + 169 * MiB);
    float*          bc2   = (float*)(ws + 169 * MiB);   // reuses dead region
    unsigned short* Wx16  = (unsigned short*)(ws + 171 * MiB);
    unsigned short* Wdt16 = (unsigned short*)(ws + 172 * MiB);
    unsigned short* Wo16  = (unsigned short*)(ws + 173 * MiB);

    dim3 blk(256);

    // bf16 conversions
    cvt_f32_bf16<<<8192, blk, 0, stream>>>(hs, hs16, 2097152);
    cvt_f32_bf16<<<4096, blk, 0, stream>>>(in_proj_w, W1_16, 1048576);
    cvt_f32_bf16<<<512, blk, 0, stream>>>(x_proj_w, Wx16, 131072);
    cvt_f32_bf16<<<256, blk, 0, stream>>>(dt_proj_w, Wdt16, 65536);
    cvt_f32_bf16<<<2048, blk, 0, stream>>>(out_proj_w, Wo16, 524288);

    // 1) xT[d][m] = W1x . hs^T   (M=2048, N=8192, K=1024)
    gemm_bf16<<<dim3(64, 16), blk, 0, stream>>>(
        W1_16, D_MODEL, hs16, D_MODEL, xT, BL, D_MODEL, nullptr, 0);

    // 2) zT[d][m] = silu(W1z . hs^T)
    gemm_bf16<<<dim3(64, 16), blk, 0, stream>>>(
        W1_16 + (size_t)D_INNER * D_MODEL, D_MODEL, hs16, D_MODEL,
        zT, BL, D_MODEL, nullptr, 2);

    // 3) xcT16 = bf16(silu(conv(xT) + b))
    conv_silu_kernel<<<(D_INNER * (BL / 4)) / 256, blk, 0, stream>>>(
        xT, conv_w, conv_b, xcT16);

    // 4) xc16[m][d] = transpose(xcT16)
    transpose_bf16<<<dim3(BL / 32, D_INNER / 32), blk, 0, stream>>>(
        xcT16, BL, xc16, D_INNER);

    // 5) xdbl[m][256] = xc . x_proj^T   (M=8192, N=256, K=2048)
    gemm_bf16<<<dim3(2, 64), blk, 0, stream>>>(
        xc16, D_INNER, Wx16, D_INNER, xdbl, 256, D_INNER, nullptr, 0);

    // 6) xdbl16 = bf16(xdbl[:, :128])
    cvt_dtpart<<<1024, blk, 0, stream>>>(xdbl, xdbl16);

    // 7) dtT[d][m] = softplus(Wdt . xdbl_dt^T + b[d])  (M=2048, N=8192, K=128)
    gemm_bf16<<<dim3(64, 16), blk, 0, stream>>>(
        Wdt16, DT_RANK, xdbl16, DT_RANK, dtT, BL, DT_RANK, dt_proj_b, 1);

    // 7b) pack B/C for b128 LDS reads in the scan
    repack_bc<<<1024, blk, 0, stream>>>(xdbl, bc2);

    // 8) single-pass scan: 1 wave per (b,d), 8 waves/block, packed B/C LDS
    scan_seq_kernel<<<512, dim3(512), 0, stream>>>(
        dtT, xcT16, bc2, zT, A_log, Dp);

    // 9) y16[m][d] = bf16(transpose(zT))
    transpose_f32_bf16<<<dim3(BL / 32, D_INNER / 32), blk, 0, stream>>>(
        zT, BL, y16, D_INNER);

    // 10) out = y . out_proj^T   (M=8192, N=1024, K=2048)
    gemm_bf16<<<dim3(8, 64), blk, 0, stream>>>(
        y16, D_INNER, Wo16, D_INNER, out, D_MODEL, D_INNER, nullptr, 0);
}

// Round 15
// 780.677 us; speedup vs baseline: 1.1514x; 1.0730x over previous
//
#include <hip/hip_runtime.h>
#include <math.h>

// Problem constants (fixed by the reference)
#define B_SZ 2
#define L_SEQ 4096
#define D_MODEL 1024
#define D_INNER 2048
#define D_STATE 64
#define DT_RANK 128
#define BL (B_SZ * L_SEQ)          // 8192 tokens

#define AS1 __attribute__((address_space(1)))
#define AS3 __attribute__((address_space(3)))

typedef __attribute__((ext_vector_type(8))) short bf16x8_t;  // 8 bf16 = 4 VGPRs
typedef __attribute__((ext_vector_type(4))) float f32x4_t;
typedef __attribute__((ext_vector_type(2))) float f32x2_t;
typedef __attribute__((ext_vector_type(2))) unsigned int u32x2_t;

__device__ __forceinline__ unsigned short f2bf(float f) {
    unsigned int u = __float_as_uint(f);
    u = (u + 0x7FFFu + ((u >> 16) & 1u)) >> 16;   // RNE
    return (unsigned short)u;
}
__device__ __forceinline__ float bf2f(unsigned short h) {
    return __uint_as_float(((unsigned int)h) << 16);
}

// ---------------------------------------------------------------------------
// fp32 -> bf16 bulk convert (n4 = count of float4 groups)
// ---------------------------------------------------------------------------
__global__ __launch_bounds__(256) void cvt_f32_bf16(
    const float* __restrict__ in, unsigned short* __restrict__ out, int n4)
{
    int i = blockIdx.x * 256 + threadIdx.x;
    if (i >= n4) return;
    float4 v = ((const float4*)in)[i];
    ushort4 o;
    o.x = f2bf(v.x); o.y = f2bf(v.y); o.z = f2bf(v.z); o.w = f2bf(v.w);
    ((ushort4*)out)[i] = o;
}

// xdbl[:, :128] (fp32, row stride 256) -> packed bf16 [8192][128]
__global__ __launch_bounds__(256) void cvt_dtpart(
    const float* __restrict__ xdbl, unsigned short* __restrict__ out)
{
    int i = blockIdx.x * 256 + threadIdx.x;   // 0 .. 8192*32-1
    int m = i >> 5, c = i & 31;
    float4 v = *(const float4*)(xdbl + (size_t)m * 256 + c * 4);
    ushort4 o;
    o.x = f2bf(v.x); o.y = f2bf(v.y); o.z = f2bf(v.z); o.w = f2bf(v.w);
    ((ushort4*)(out))[(size_t)m * 32 + c] = o;
}

// B/C repack: bc2[t>>2][n][t&3] = xdbl[t][128+n]  (n=0..127; B at n<64, C at
// n>=64). Makes 4 consecutive steps' B (or C) for one lane a contiguous 16B
// quad -> scan reads b128 instead of 4x b32. 4MB r + 4MB w, ~4us.
__global__ __launch_bounds__(256) void repack_bc(
    const float* __restrict__ xdbl,   // [8192][256]
    float* __restrict__ bc2)          // [2048][128][4]
{
    int i = blockIdx.x * 256 + threadIdx.x;   // 0 .. 262143
    int t4 = i >> 7, n = i & 127;
    const float* s = xdbl + (size_t)(t4 * 4) * 256 + 128 + n;
    float4 o;
    o.x = s[0]; o.y = s[256]; o.z = s[512]; o.w = s[768];
    ((float4*)bc2)[i] = o;
}

// ---------------------------------------------------------------------------
// bf16 MFMA GEMM: C[m][n] = act( sum_k A[m][k]*B[n][k] [+ bias[m]] )
// act: 0 none, 1 softplus (bias by row; branchless stable fast-math form),
// 2 silu. R13's T1 XCD swizzle REVERTED: measured -17us (all operands are
// L3-fit; guide m160: swizzle costs ~2% when L3-resident).
// ---------------------------------------------------------------------------
__global__ __launch_bounds__(256) void gemm_bf16(
    const unsigned short* __restrict__ A, int lda,
    const unsigned short* __restrict__ B, int ldb,
    float* __restrict__ C, int ldc, int K,
    const float* __restrict__ bias, int act)
{
    __shared__ unsigned short As[128 * 32];   // [row][k] linear, no pad
    __shared__ unsigned short Bs[128 * 32];

    const int tid = threadIdx.x;
    const int w = tid >> 6, lane = tid & 63;
    const int bm = blockIdx.y * 128, bn = blockIdx.x * 128;
    const int wm = (w & 1) * 64, wn = (w >> 1) * 64;

    f32x4_t acc[4][4];
#pragma unroll
    for (int i = 0; i < 4; ++i)
#pragma unroll
        for (int j = 0; j < 4; ++j) acc[i][j] = (f32x4_t){0.f, 0.f, 0.f, 0.f};

    const int srow = lane >> 2;
    const int scol = (lane & 3) * 8;
    const unsigned short* Ag0 = A + (size_t)(bm + w * 16 + srow) * lda + scol;
    const unsigned short* Ag1 = A + (size_t)(bm + 64 + w * 16 + srow) * lda + scol;
    const unsigned short* Bg0 = B + (size_t)(bn + w * 16 + srow) * ldb + scol;
    const unsigned short* Bg1 = B + (size_t)(bn + 64 + w * 16 + srow) * ldb + scol;
    unsigned short* la0 = &As[(w * 16) * 32];
    unsigned short* la1 = &As[(64 + w * 16) * 32];
    unsigned short* lb0 = &Bs[(w * 16) * 32];
    unsigned short* lb1 = &Bs[(64 + w * 16) * 32];

    const int fr = lane & 15;
    const int fk = (lane >> 4) * 8;

    for (int k0 = 0; k0 < K; k0 += 32) {
        __syncthreads();
        __builtin_amdgcn_global_load_lds((const AS1 void*)(Ag0 + k0), (AS3 void*)la0, 16, 0, 0);
        __builtin_amdgcn_global_load_lds((const AS1 void*)(Ag1 + k0), (AS3 void*)la1, 16, 0, 0);
        __builtin_amdgcn_global_load_lds((const AS1 void*)(Bg0 + k0), (AS3 void*)lb0, 16, 0, 0);
        __builtin_amdgcn_global_load_lds((const AS1 void*)(Bg1 + k0), (AS3 void*)lb1, 16, 0, 0);
        __syncthreads();

        bf16x8_t af[4], bfr[4];
#pragma unroll
        for (int i = 0; i < 4; ++i)
            af[i] = *(const bf16x8_t*)&As[(wm + i * 16 + fr) * 32 + fk];
#pragma unroll
        for (int j = 0; j < 4; ++j)
            bfr[j] = *(const bf16x8_t*)&Bs[(wn + j * 16 + fr) * 32 + fk];
#pragma unroll
        for (int i = 0; i < 4; ++i)
#pragma unroll
            for (int j = 0; j < 4; ++j)
                acc[i][j] = __builtin_amdgcn_mfma_f32_16x16x32_bf16(
                    af[i], bfr[j], acc[i][j], 0, 0, 0);
    }

    const int erow = (lane >> 4) * 4;
    const int ecol = lane & 15;
#pragma unroll
    for (int i = 0; i < 4; ++i) {
        int gr0 = bm + wm + i * 16 + erow;
#pragma unroll
        for (int j = 0; j < 4; ++j) {
            int gc = bn + wn + j * 16 + ecol;
#pragma unroll
            for (int r = 0; r < 4; ++r) {
                float v = acc[i][j][r];
                if (act == 1) {
                    // branchless stable softplus: max(t,0)+log(1+exp(-|t|))
                    float t = v + bias[gr0 + r];
                    v = fmaxf(t, 0.f) + __logf(1.f + __expf(-fabsf(t)));
                } else if (act == 2) {
                    v = v / (1.f + __expf(-v));
                }
                C[(size_t)(gr0 + r) * ldc + gc] = v;
            }
        }
    }
}

// ---------------------------------------------------------------------------
// causal depthwise conv (k=4) + bias + silu on [d][m] layout, bf16 output.
// ---------------------------------------------------------------------------
__global__ __launch_bounds__(256) void conv_silu_kernel(
    const float* __restrict__ xT,     // [2048][8192] fp32
    const float* __restrict__ w,      // [2048][4]
    const float* __restrict__ bias,   // [2048]
    unsigned short* __restrict__ xcT16) // [2048][8192] bf16
{
    int gid = blockIdx.x * blockDim.x + threadIdx.x;  // 0 .. 2048*2048-1
    int d = gid >> 11;
    int c4 = gid & 2047;
    int m0 = c4 * 4;
    int l0 = m0 & (L_SEQ - 1);

    const float* row = xT + (size_t)d * BL;
    float4 v = *(const float4*)(row + m0);
    float4 p;
    if (l0 == 0) { p.x = p.y = p.z = p.w = 0.f; }
    else         { p = *(const float4*)(row + m0 - 4); }

    float4 wv = ((const float4*)w)[d];
    float bb = bias[d];
    float e[4];
    e[0] = bb + wv.x * p.y + wv.y * p.z + wv.z * p.w + wv.w * v.x;
    e[1] = bb + wv.x * p.z + wv.y * p.w + wv.z * v.x + wv.w * v.y;
    e[2] = bb + wv.x * p.w + wv.y * v.x + wv.z * v.y + wv.w * v.z;
    e[3] = bb + wv.x * v.x + wv.y * v.y + wv.z * v.z + wv.w * v.w;
    ushort4 o;
    o.x = f2bf(e[0] / (1.f + __expf(-e[0])));
    o.y = f2bf(e[1] / (1.f + __expf(-e[1])));
    o.z = f2bf(e[2] / (1.f + __expf(-e[2])));
    o.w = f2bf(e[3] / (1.f + __expf(-e[3])));
    ((ushort4*)(xcT16 + (size_t)d * BL))[c4] = o;
}

// ---------------------------------------------------------------------------
// 32x32 tiled transposes (coalesced both sides)
// ---------------------------------------------------------------------------
__global__ __launch_bounds__(256) void transpose_f32_bf16(
    const float* __restrict__ in, int ldin,
    unsigned short* __restrict__ out, int ldout)
{
    __shared__ float tl[32][33];
    int r0 = blockIdx.y * 32, c0 = blockIdx.x * 32;
    int tx = threadIdx.x & 31, ty = threadIdx.x >> 5;
#pragma unroll
    for (int k = 0; k < 4; ++k)
        tl[ty + 8 * k][tx] = in[(size_t)(r0 + ty + 8 * k) * ldin + c0 + tx];
    __syncthreads();
#pragma unroll
    for (int k = 0; k < 4; ++k)
        out[(size_t)(c0 + ty + 8 * k) * ldout + r0 + tx] = f2bf(tl[tx][ty + 8 * k]);
}

__global__ __launch_bounds__(256) void transpose_bf16(
    const unsigned short* __restrict__ in, int ldin,
    unsigned short* __restrict__ out, int ldout)
{
    __shared__ unsigned short tl[32][33];
    int r0 = blockIdx.y * 32, c0 = blockIdx.x * 32;
    int tx = threadIdx.x & 31, ty = threadIdx.x >> 5;
#pragma unroll
    for (int k = 0; k < 4; ++k)
        tl[ty + 8 * k][tx] = in[(size_t)(r0 + ty + 8 * k) * ldin + c0 + tx];
    __syncthreads();
#pragma unroll
    for (int k = 0; k < 4; ++k)
        out[(size_t)(c0 + ty + 8 * k) * ldout + r0 + tx] = tl[tx][ty + 8 * k];
}

// ---------------------------------------------------------------------------
// Single-pass selective scan (R10 config, measured 378us stable across
// R12/R13: FETCH 97MB / WRITE 66MB / VALUBusy 74%): ONE WAVE per (b,d);
// 8 waves/block sharing one batch's packed B/C via double-buffered 32-step
// LDS windows. WSTEPS=32 is load-bearing (R11: 16-step windows -> partial-
// line y writes -> WRITE 139MB, +85us). Techniques: shared-B/C LDS staging
// (R6), dtx premult (R8), b128 packed B/C reads (R9), v_pk f32 packing
// (R10), permlane32/16 folds + DPP quad_perm butterflies. Near the VALU
// issue floor for this decomposition.
// ---------------------------------------------------------------------------
#define SCHUNK 512
#define WSTEPS 32     // B/C window

#if __has_builtin(__builtin_amdgcn_permlane32_swap)
#define HAVE_PL32 1
#endif
#if __has_builtin(__builtin_amdgcn_permlane16_swap)
#define HAVE_PL16 1
#endif

// Packed fold stage 1 (xor32): pr2[i] (t=2i,2i+1) folded with pr2[i+4] (t+8).
// Per component: identical to R5-verified pl32_fold(x,y) = r.x + r.y.
#ifdef HAVE_PL32
#define FOLD_S1_PK                                                           \
    _Pragma("unroll")                                                        \
    for (int i = 0; i < 4; ++i) {                                            \
        f32x2_t xx = dir32 ? pr2[i + 4] : pr2[i];                            \
        f32x2_t yy = dir32 ? pr2[i] : pr2[i + 4];                            \
        u32x2_t ra = __builtin_amdgcn_permlane32_swap(                       \
            __float_as_uint(xx.x), __float_as_uint(yy.x), false, false);     \
        u32x2_t rb = __builtin_amdgcn_permlane32_swap(                       \
            __float_as_uint(xx.y), __float_as_uint(yy.y), false, false);     \
        f32x2_t va = {__uint_as_float(ra.x), __uint_as_float(rb.x)};         \
        f32x2_t vb = {__uint_as_float(ra.y), __uint_as_float(rb.y)};         \
        pr2[i] = va + vb;                                                    \
    }
#else
#define FOLD_S1_PK                                                           \
    _Pragma("unroll")                                                        \
    for (int i = 0; i < 4; ++i) {                                            \
        _Pragma("unroll")                                                    \
        for (int u = 0; u < 2; ++u) {                                        \
            float p0 = u ? pr2[i].y : pr2[i].x;                              \
            float p8 = u ? pr2[i + 4].y : pr2[i + 4].x;                      \
            float send = (lane & 32) ? p0 : p8;                              \
            float recv = __shfl_xor(send, 32);                               \
            float res = ((lane & 32) ? p8 : p0) + recv;                      \
            if (u) pr2[i].y = res; else pr2[i].x = res;                      \
        }                                                                    \
    }
#endif

// Packed fold stage 2 (xor16): pr2[i] folded with pr2[i+2], i<2.
#ifdef HAVE_PL16
#define FOLD_S2_PK                                                           \
    _Pragma("unroll")                                                        \
    for (int i = 0; i < 2; ++i) {                                            \
        f32x2_t xx = dir16 ? pr2[i + 2] : pr2[i];                            \
        f32x2_t yy = dir16 ? pr2[i] : pr2[i + 2];                            \
        u32x2_t ra = __builtin_amdgcn_permlane16_swap(                       \
            __float_as_uint(xx.x), __float_as_uint(yy.x), false, false);     \
        u32x2_t rb = __builtin_amdgcn_permlane16_swap(                       \
            __float_as_uint(xx.y), __float_as_uint(yy.y), false, false);     \
        f32x2_t va = {__uint_as_float(ra.x), __uint_as_float(rb.x)};         \
        f32x2_t vb = {__uint_as_float(ra.y), __uint_as_float(rb.y)};         \
        pr2[i] = va + vb;                                                    \
    }
#else
#define FOLD_S2_PK                                                           \
    _Pragma("unroll")                                                        \
    for (int i = 0; i < 2; ++i) {                                            \
        _Pragma("unroll")                                                    \
        for (int u = 0; u < 2; ++u) {                                        \
            float p0 = u ? pr2[i].y : pr2[i].x;                              \
            float p4 = u ? pr2[i + 2].y : pr2[i + 2].x;                      \
            float send = (lane & 16) ? p0 : p4;                              \
            float recv = __shfl_xor(send, 16);                               \
            float res = ((lane & 16) ? p4 : p0) + recv;                      \
            if (u) pr2[i].y = res; else pr2[i].x = res;                      \
        }                                                                    \
    }
#endif

// xor2 then xor1 butterfly on V: DPP quad_perm (stays within quads).
#if __has_builtin(__builtin_amdgcn_mov_dpp)
#define BFLY21(V)                                                            \
    V += __int_as_float(__builtin_amdgcn_mov_dpp(                            \
             __float_as_int(V), 0x4E, 0xF, 0xF, true));                      \
    V += __int_as_float(__builtin_amdgcn_mov_dpp(                            \
             __float_as_int(V), 0xB1, 0xF, 0xF, true));
#else
#define BFLY21(V)                                                            \
    V += __shfl_xor(V, 2);                                                   \
    V += __shfl_xor(V, 1);
#endif

// Cooperative async stage of window W's packed B/C (16KB linear) into
// s_bc2[DB]. Each wave copies 2x 1KB (64 lanes x 16B); global src per-lane,
// LDS dest wave-uniform base (+lane*16 by HW).
#define STAGE_BC(W, DB)                                                      \
{                                                                            \
    const float* wbase_ = bc2 + (size_t)(bQ + 8u * (unsigned)(W)) * 512;     \
    _Pragma("unroll")                                                        \
    for (int r_ = 0; r_ < 2; ++r_) {                                         \
        const float* src_ = wbase_ + (wid * 2 + r_) * 256 + lane * 4;        \
        __builtin_amdgcn_global_load_lds((const AS1 void*)src_,              \
            (AS3 void*)&s_bc2[DB][(wid * 2 + r_) * 256], 16, 0, 0);          \
    }                                                                        \
}

#define GROUP16(GG2, ZV)                                                     \
{                                                                            \
    const int gp = gpos + (GG2);        /* step base within chunk */         \
    const int t4b = (GG2) >> 2;                                              \
    f32x4_t bv4[4], cv4[4];                                                  \
    _Pragma("unroll")                                                        \
    for (int a = 0; a < 4; ++a) {       /* b128: 4 steps' B (or C) per read */\
        bv4[a] = *(const f32x4_t*)&sbcw[(t4b + a) * 512 + lane * 4];         \
        cv4[a] = *(const f32x4_t*)&sbcw[(t4b + a) * 512 + 256 + lane * 4];   \
    }                                                                        \
    f32x4_t d44[4], x44[4];                                                  \
    d44[0] = *(const f32x4_t*)&sdt[gp];                                      \
    d44[1] = *(const f32x4_t*)&sdt[gp + 4];                                  \
    d44[2] = *(const f32x4_t*)&sdt[gp + 8];                                  \
    d44[3] = *(const f32x4_t*)&sdt[gp + 12];                                 \
    x44[0] = *(const f32x4_t*)&sdtx[gp];                                     \
    x44[1] = *(const f32x4_t*)&sdtx[gp + 4];                                 \
    x44[2] = *(const f32x4_t*)&sdtx[gp + 8];                                 \
    x44[3] = *(const f32x4_t*)&sdtx[gp + 12];                                \
    f32x2_t e2[8], ib2[8], cvp[8];                                           \
    _Pragma("unroll")                                                        \
    for (int a = 0; a < 4; ++a) {       /* packed muls: v_pk_mul_f32 */      \
        e2[2*a]    = __builtin_shufflevector(d44[a], d44[a], 0, 1) * An2v;   \
        e2[2*a+1]  = __builtin_shufflevector(d44[a], d44[a], 2, 3) * An2v;   \
        ib2[2*a]   = __builtin_shufflevector(x44[a], x44[a], 0, 1)           \
                   * __builtin_shufflevector(bv4[a], bv4[a], 0, 1);          \
        ib2[2*a+1] = __builtin_shufflevector(x44[a], x44[a], 2, 3)           \
                   * __builtin_shufflevector(bv4[a], bv4[a], 2, 3);          \
        cvp[2*a]   = __builtin_shufflevector(cv4[a], cv4[a], 0, 1);          \
        cvp[2*a+1] = __builtin_shufflevector(cv4[a], cv4[a], 2, 3);          \
    }                                                                        \
    f32x2_t pr2[8];                                                          \
    _Pragma("unroll")                                                        \
    for (int i = 0; i < 8; ++i) {       /* serial h chain; packed h*C */     \
        float a0 = __builtin_amdgcn_exp2f(e2[i].x);                          \
        float a1 = __builtin_amdgcn_exp2f(e2[i].y);                          \
        f32x2_t hh;                                                          \
        h = fmaf(h, a0, ib2[i].x); hh.x = h;                                 \
        h = fmaf(h, a1, ib2[i].y); hh.y = h;                                 \
        pr2[i] = hh * cvp[i];                                                \
    }                                                                        \
    FOLD_S1_PK;                                                              \
    FOLD_S2_PK;                                                              \
    float prr[4] = {pr2[0].x, pr2[0].y, pr2[1].x, pr2[1].y};                 \
    _Pragma("unroll")                                                        \
    for (int t = 0; t < 2; ++t) {       /* fold xor8: 4 -> 2 */              \
        float send = (lane & 8) ? prr[t] : prr[t + 2];                       \
        float recv = __shfl_xor(send, 8);                                    \
        prr[t] = ((lane & 8) ? prr[t + 2] : prr[t]) + recv;                  \
    }                                                                        \
    {                                   /* fold xor4: 2 -> 1 */              \
        float send = (lane & 4) ? prr[0] : prr[1];                           \
        float recv = __shfl_xor(send, 4);                                    \
        prr[0] = ((lane & 4) ? prr[1] : prr[0]) + recv;                      \
    }                                                                        \
    BFLY21(prr[0]);                     /* butterfly over 4 n-residues */    \
    if ((lane & 3) == 0) {              /* 16 writer lanes, step (lane>>2)&15 */ \
        float xv = bf2f(sx[gp + myt16]);                                     \
        zrow[cbase + gp + myt16] = fmaf(Dd, xv, prr[0]) * (ZV);              \
    }                                                                        \
}

__global__ __launch_bounds__(512, 4) void scan_seq_kernel(
    const float* __restrict__ dtT,           // [2048][8192] fp32
    const unsigned short* __restrict__ xcT16,// [2048][8192] bf16
    const float* __restrict__ bc2,           // [2048][128][4] packed B/C
    float* __restrict__ zyT,                 // [2048][8192]: silu(z) in, y out
    const float* __restrict__ A_log,         // [2048][64]
    const float* __restrict__ Dp)            // [2048]
{
    __shared__ __align__(16) float s_dt[8][SCHUNK];           // 16 KB
    __shared__ __align__(16) float s_dtx[8][SCHUNK];          // 16 KB
    __shared__ __align__(16) unsigned short s_x[8][SCHUNK];   // 8 KB
    __shared__ __align__(16) float s_bc2[2][WSTEPS * 128];    // 32 KB (packed B/C)
    // 72 KB/block -> 2 blocks/CU, 16 waves/CU, 512 blocks = 1 round

    const int tid  = threadIdx.x;
    const int wid  = tid >> 6;              // 0..7
    const int lane = tid & 63;
    const int bi   = blockIdx.x;            // 0..511; bi&1 constant per XCD
    const int b    = bi & 1;                // all 8 waves share b -> shared B/C
    const int d    = (bi >> 1) * 8 + wid;
    const unsigned bQ = (unsigned)b * (L_SEQ / 4);   // t4 offset of this batch

    const size_t rowbase = (size_t)d * BL + (size_t)(b * L_SEQ);
    const float An2 = -__expf(A_log[d * D_STATE + lane]) * 1.44269504f;
    const f32x2_t An2v = {An2, An2};
    const float Dd  = Dp[d];

    // permlane swap-direction probes (uniform, once; HW-verified in R5)
#ifdef HAVE_PL32
    bool dir32;
    {
        u32x2_t r = __builtin_amdgcn_permlane32_swap((unsigned)lane,
                        (unsigned)lane + 1000u, false, false);
        dir32 = (__builtin_amdgcn_readfirstlane(r.x) == 1032u);
    }
#endif
#ifdef HAVE_PL16
    bool dir16;
    {
        u32x2_t r = __builtin_amdgcn_permlane16_swap((unsigned)lane,
                        (unsigned)lane + 1000u, false, false);
        dir16 = (__builtin_amdgcn_readfirstlane(r.x) == 1016u);
    }
#endif

    float* sdt = s_dt[wid];
    float* sdtx = s_dtx[wid];
    unsigned short* sx = s_x[wid];
    const float* dtrow = dtT + rowbase;
    const unsigned short* xrow = xcT16 + rowbase;
    float* zrow = zyT + rowbase;
    const int myt16 = (lane >> 2) & 15;     // step index this lane ends up with

    // prefetch chunk 0. dt loaded in the SAME element range as x (8 elems
    // per lane): pA = elems 8*lane..+3, pB = 8*lane+4..+7, pX = 8 bf16.
    float4 pA = ((const float4*)dtrow)[2 * lane];
    float4 pB = ((const float4*)dtrow)[2 * lane + 1];
    uint4  pX = ((const uint4*)xrow)[lane];

    float h = 0.f;
    int buf = 0;

    STAGE_BC(0, 0);                          // prologue: window 0 -> buf 0
    __syncthreads();

    for (int c = 0; c < L_SEQ / SCHUNK; ++c) {
        // stage current chunk's dt/x/dtx to this wave's private LDS slice.
        // dtx = dt*x computed ONCE here (amortized over 32 groups).
        ((float4*)sdt)[2 * lane]     = pA;
        ((float4*)sdt)[2 * lane + 1] = pB;
        ((uint4*)sx)[lane]           = pX;
        float4 dxA, dxB;
        dxA.x = pA.x * __uint_as_float(pX.x << 16);
        dxA.y = pA.y * __uint_as_float(pX.x & 0xffff0000u);
        dxA.z = pA.z * __uint_as_float(pX.y << 16);
        dxA.w = pA.w * __uint_as_float(pX.y & 0xffff0000u);
        dxB.x = pB.x * __uint_as_float(pX.z << 16);
        dxB.y = pB.y * __uint_as_float(pX.z & 0xffff0000u);
        dxB.z = pB.z * __uint_as_float(pX.w << 16);
        dxB.w = pB.w * __uint_as_float(pX.w & 0xffff0000u);
        ((float4*)sdtx)[2 * lane]     = dxA;
        ((float4*)sdtx)[2 * lane + 1] = dxB;

        if (c < L_SEQ / SCHUNK - 1) {       // register-prefetch next chunk
            pA = ((const float4*)(dtrow + (c + 1) * SCHUNK))[2 * lane];
            pB = ((const float4*)(dtrow + (c + 1) * SCHUNK))[2 * lane + 1];
            pX = ((const uint4*)(xrow + (c + 1) * SCHUNK))[lane];
        }
        const int cbase = c * SCHUNK;

        for (int wd = 0; wd < SCHUNK / WSTEPS; ++wd) {
            const int wglob = c * (SCHUNK / WSTEPS) + wd;
            if (wglob + 1 < L_SEQ / WSTEPS)  // issue next window's staging EARLY
                STAGE_BC(wglob + 1, buf ^ 1);
            const int gpos = wd * WSTEPS;
            // hoist z for both groups: full-group latency cover
            float zv0 = 0.f, zv1 = 0.f;
            if ((lane & 3) == 0) {
                zv0 = zrow[cbase + gpos + myt16];
                zv1 = zrow[cbase + gpos + 16 + myt16];
            }
            const float* sbcw = s_bc2[buf];
            GROUP16(0, zv0);
            GROUP16(16, zv1);
            __syncthreads();                 // staging had a full window to land
            buf ^= 1;
        }
    }
}

// ---------------------------------------------------------------------------
extern "C" void kernel_launch(void* const* d_in, const int* in_sizes, int n_in,
                              void* d_out, int out_size, void* d_ws, size_t ws_size,
                              hipStream_t stream)
{
    const float* hs        = (const float*)d_in[0];  // [8192][1024]
    const float* in_proj_w = (const float*)d_in[1];  // [4096][1024]
    const float* conv_w    = (const float*)d_in[2];  // [2048][4]
    const float* conv_b    = (const float*)d_in[3];  // [2048]
    const float* x_proj_w  = (const float*)d_in[4];  // [256][2048]
    const float* dt_proj_w = (const float*)d_in[5];  // [2048][128]
    const float* dt_proj_b = (const float*)d_in[6];  // [2048]
    const float* A_log     = (const float*)d_in[7];  // [2048][64]
    const float* Dp        = (const float*)d_in[8];  // [2048]
    const float* out_proj_w= (const float*)d_in[9];  // [1024][2048]
    float* out = (float*)d_out;                      // [8192][1024]

    // workspace map (MiB offsets; peak ~177.5 MiB) -- R10 layout:
    //  S0 @0   : xT fp32 (64) -> xc16 bf16 (32) @0 -> dtT fp32 (64) @0
    //  S1 @64  : zT fp32 (64)  (scan writes y in place)
    //  S2 @128 : W1_16 (8)@128 + hs16 (16)@136 -> xcT16 bf16 (32)@128 -> y16 (32)@128
    //  tail    : xdbl fp32 (8)@160, xdbl16 (2)@169 -> bc2 (4)@169 (xdbl16,
    //            Wx16, Wdt16 all dead by repack time), Wx16 (1)@171,
    //            Wdt16 (.5)@172, Wo16 (4)@173  (end 177)
    char* ws = (char*)d_ws;
    const size_t MiB = 1024 * 1024;
    float*          xT    = (float*)(ws);
    unsigned short* xc16  = (unsigned short*)(ws);
    float*          dtT   = (float*)(ws);
    float*          zT    = (float*)(ws + 64 * MiB);
    unsigned short* W1_16 = (unsigned short*)(ws + 128 * MiB);
    unsigned short* hs16  = (unsigned short*)(ws + 136 * MiB);
    unsigned short* xcT16 = (unsigned short*)(ws + 128 * MiB);
    unsigned short* y16   = (unsigned short*)(ws + 128 * MiB);
    float*          xdbl  = (float*)(ws + 160 * MiB);
    unsigned short* xdbl16= (unsigned short*)(ws + 169 * MiB);
    float*          bc2   = (float*)(ws + 169 * MiB);   // reuses dead region
    unsigned short* Wx16  = (unsigned short*)(ws + 171 * MiB);
    unsigned short* Wdt16 = (unsigned short*)(ws + 172 * MiB);
    unsigned short* Wo16  = (unsigned short*)(ws + 173 * MiB);

    dim3 blk(256);

    // bf16 conversions
    cvt_f32_bf16<<<8192, blk, 0, stream>>>(hs, hs16, 2097152);
    cvt_f32_bf16<<<4096, blk, 0, stream>>>(in_proj_w, W1_16, 1048576);
    cvt_f32_bf16<<<512, blk, 0, stream>>>(x_proj_w, Wx16, 131072);
    cvt_f32_bf16<<<256, blk, 0, stream>>>(dt_proj_w, Wdt16, 65536);
    cvt_f32_bf16<<<2048, blk, 0, stream>>>(out_proj_w, Wo16, 524288);

    // 1) xT[d][m] = W1x . hs^T   (M=2048, N=8192, K=1024)
    gemm_bf16<<<dim3(64, 16), blk, 0, stream>>>(
        W1_16, D_MODEL, hs16, D_MODEL, xT, BL, D_MODEL, nullptr, 0);

    // 2) zT[d][m] = silu(W1z . hs^T)
    gemm_bf16<<<dim3(64, 16), blk, 0, stream>>>(
        W1_16 + (size_t)D_INNER * D_MODEL, D_MODEL, hs16, D_MODEL,
        zT, BL, D_MODEL, nullptr, 2);

    // 3) xcT16 = bf16(silu(conv(xT) + b))
    conv_silu_kernel<<<(D_INNER * (BL / 4)) / 256, blk, 0, stream>>>(
        xT, conv_w, conv_b, xcT16);

    // 4) xc16[m][d] = transpose(xcT16)
    transpose_bf16<<<dim3(BL / 32, D_INNER / 32), blk, 0, stream>>>(
        xcT16, BL, xc16, D_INNER);

    // 5) xdbl[m][256] = xc . x_proj^T   (M=8192, N=256, K=2048)
    gemm_bf16<<<dim3(2, 64), blk, 0, stream>>>(
        xc16, D_INNER, Wx16, D_INNER, xdbl, 256, D_INNER, nullptr, 0);

    // 6) xdbl16 = bf16(xdbl[:, :128])
    cvt_dtpart<<<1024, blk, 0, stream>>>(xdbl, xdbl16);

    // 7) dtT[d][m] = softplus(Wdt . xdbl_dt^T + b[d])  (M=2048, N=8192, K=128)
    gemm_bf16<<<dim3(64, 16), blk, 0, stream>>>(
        Wdt16, DT_RANK, xdbl16, DT_RANK, dtT, BL, DT_RANK, dt_proj_b, 1);

    // 7b) pack B/C for b128 LDS reads in the scan
    repack_bc<<<1024, blk, 0, stream>>>(xdbl, bc2);

    // 8) single-pass scan: 1 wave per (b,d), 8 waves/block, packed B/C LDS
    scan_seq_kernel<<<512, dim3(512), 0, stream>>>(
        dtT, xcT16, bc2, zT, A_log, Dp);

    // 9) y16[m][d] = bf16(transpose(zT))
    transpose_f32_bf16<<<dim3(BL / 32, D_INNER / 32), blk, 0, stream>>>(
        zT, BL, y16, D_INNER);

    // 10) out = y . out_proj^T   (M=8192, N=1024, K=2048)
    gemm_bf16<<<dim3(8, 64), blk, 0, stream>>>(
        y16, D_INNER, Wo16, D_INNER, out, D_MODEL, D_INNER, nullptr, 0);
}